// Round 10
// baseline (1868.860 us; speedup 1.0000x reference)
//
#include <hip/hip_runtime.h>
#include <cstddef>
#include <cstdint>

typedef __attribute__((ext_vector_type(8))) short short8v;
typedef __attribute__((ext_vector_type(4))) short short4v;
typedef __attribute__((ext_vector_type(4))) float floatx4;

__device__ __forceinline__ float b2f(short u){
    return __uint_as_float(((unsigned)(unsigned short)u) << 16);
}
__device__ __forceinline__ short f2b(float f){
    unsigned x = __float_as_uint(f);
    unsigned r = x + 0x7FFFu + ((x >> 16) & 1u);
    return (short)(r >> 16);
}
__device__ __forceinline__ float loadF(const void* p, size_t i, int isBf16){
    return isBf16 ? b2f(((const short*)p)[i]) : ((const float*)p)[i];
}
__device__ __forceinline__ int loadI(const void* p, size_t i, int isI64){
    return isI64 ? ((const int*)p)[2 * i] : ((const int*)p)[i];
}
// async global->LDS, 16B per lane; dest = lds_base + lane*16 (wave-uniform base)
__device__ __forceinline__ void gload16(const void* g, void* l){
    __builtin_amdgcn_global_load_lds(
        (const __attribute__((address_space(1))) void*)g,
        (__attribute__((address_space(3))) void*)l, 16, 0, 0);
}

// ---- DPP wave64 sum: quad_perm x2, half_mirror, mirror, bcast15, bcast31, readlane ----
template<int CTRL, int RM>
__device__ __forceinline__ float dppAdd(float p){
    int t = __builtin_amdgcn_update_dpp(0, __float_as_int(p), CTRL, RM, 0xF, true);
    return p + __int_as_float(t);
}
__device__ __forceinline__ float waveSum(float p){
    p = dppAdd<0xB1, 0xF>(p);    // xor 1 (quad_perm 1,0,3,2)
    p = dppAdd<0x4E, 0xF>(p);    // xor 2 (quad_perm 2,3,0,1)
    p = dppAdd<0x141, 0xF>(p);   // row_half_mirror
    p = dppAdd<0x140, 0xF>(p);   // row_mirror -> each 16-row holds its sum
    p = dppAdd<0x142, 0xA>(p);   // row_bcast15 into rows 1,3
    p = dppAdd<0x143, 0xC>(p);   // row_bcast31 into rows 2,3 -> lane63 = total
    return __int_as_float(__builtin_amdgcn_readlane(__float_as_int(p), 63));
}

// ---- setup: zero cnt/fill/pool + dtype detect + sentinel (one launch) ----
// flags: [0]=floats-bf16 [1]=ints-i64 [8..10]=B-hasLo per layer
__global__ void setup_kernel(const void* feat, const void* ei, int N, int* flags,
                             int* cnt, int* fill, unsigned* pool, void* out){
    int gid = blockIdx.x * 256 + threadIdx.x;
    if (gid < N){ cnt[gid] = 0; fill[gid] = 0; }
    if (gid < 256) pool[gid] = 0u;
    if (blockIdx.x == 0){
        int t = threadIdx.x;
        if (t < 64){
            if (t >= 8 && t < 16) flags[t] = 0;
            const unsigned short* fs = (const unsigned short*)feat;
            int plaus = 0;
            for (int j = t; j < 128; j += 64){
                unsigned short s = fs[2 * j];
                int e = (s >> 7) & 0xFF;
                if (s == 0 || (e >= 100 && e <= 140)) plaus++;
            }
            #pragma unroll
            for (int o = 32; o > 0; o >>= 1) plaus += __shfl_xor(plaus, o);
            const int* ew = (const int*)ei;
            int zeros = 0;
            for (int j = t; j < 128; j += 64) if (ew[2 * j + 1] == 0) zeros++;
            #pragma unroll
            for (int o = 32; o > 0; o >>= 1) zeros += __shfl_xor(zeros, o);
            if (t == 0){
                flags[0] = (plaus >= 64) ? 1 : 0;
                flags[1] = (zeros >= 64) ? 1 : 0;
            }
        }
        __syncthreads();
        if (threadIdx.x == 0){
            if (flags[0]) ((short*)out)[0] = f2b(777.0f);
            else          ((float*)out)[0] = 777.0f;
        }
    }
}

__global__ void sentinel_kernel(void* out, const int* flags, float v){
    if (threadIdx.x == 0){
        if (flags[0]) ((short*)out)[0] = f2b(v);
        else          ((float*)out)[0] = v;
    }
}

__global__ void hist_kernel(const void* __restrict__ ei, int* __restrict__ cnt, int E,
                            const int* __restrict__ flags){
    int i = blockIdx.x * 256 + threadIdx.x;
    if (i < E) atomicAdd(&cnt[loadI(ei, (size_t)E + i, flags[1])], 1);
}

// ---- 3-phase scan ----
__global__ void scanA(const int* __restrict__ cnt, int* __restrict__ off,
                      int* __restrict__ partial, int N){
    __shared__ int wsum[16];
    const int t = threadIdx.x, w = t >> 6, lane = t & 63;
    int i = blockIdx.x * 1024 + t;
    int v = (i < N) ? cnt[i] : 0;
    int x = v;
    #pragma unroll
    for (int o = 1; o < 64; o <<= 1){
        int y = __shfl_up(x, o);
        if (lane >= o) x += y;
    }
    if (lane == 63) wsum[w] = x;
    __syncthreads();
    if (w == 0){
        int mv = (lane < 16) ? wsum[lane] : 0;
        int xx = mv;
        #pragma unroll
        for (int o = 1; o < 16; o <<= 1){
            int y = __shfl_up(xx, o);
            if (lane >= o) xx += y;
        }
        if (lane < 16) wsum[lane] = xx - mv;
    }
    __syncthreads();
    int incl = x + wsum[w];
    if (i < N) off[i] = incl - v;
    if (t == 1023) partial[blockIdx.x] = incl;
}

__global__ void scanB(int* __restrict__ partial, int* __restrict__ off, int nb, int N){
    int lane = threadIdx.x;
    int v = (lane < nb) ? partial[lane] : 0;
    int x = v;
    #pragma unroll
    for (int o = 1; o < 64; o <<= 1){
        int y = __shfl_up(x, o);
        if (lane >= o) x += y;
    }
    if (lane < nb) partial[lane] = x - v;
    if (lane == 63) off[N] = x;
}

__global__ void scanC(int* __restrict__ off, const int* __restrict__ partial, int N){
    int i = blockIdx.x * 1024 + threadIdx.x;
    if (i < N) off[i] += partial[blockIdx.x];
}

__global__ void scatter_kernel(const void* __restrict__ ei, const void* __restrict__ ea,
                               const int* __restrict__ off, int* __restrict__ fill,
                               int* __restrict__ srcS, float* __restrict__ eaS,
                               int E, const int* __restrict__ flags){
    int i = blockIdx.x * 256 + threadIdx.x;
    if (i >= E) return;
    int d = loadI(ei, (size_t)E + i, flags[1]);
    int pos = off[d] + atomicAdd(&fill[d], 1);
    srcS[pos] = loadI(ei, (size_t)i, flags[1]);
    eaS[pos] = loadF(ea, (size_t)i, flags[0]);
}

// ---- all six W [K x 256] -> Bt hi/lo in one launch; grid (256, 6) ----
struct PJobs { const void* W[6]; short* bhi[6]; short* blo[6]; int K[6]; int fidx[6]; };
__global__ void prep_all(PJobs J, int* __restrict__ flags){
    int j = blockIdx.y;
    int K = J.K[j];
    if (blockIdx.x >= K) return;
    int idx = blockIdx.x * 256 + threadIdx.x;
    int k = idx >> 8, c = idx & 255;
    float v = loadF(J.W[j], idx, flags[0]);
    short h = f2b(v);
    short l = f2b(v - b2f(h));
    J.bhi[j][(size_t)c * K + k] = h;
    J.blo[j][(size_t)c * K + k] = l;
    if (__ballot(l != 0) != 0ull && (threadIdx.x & 63) == 0) atomicOr(&flags[J.fidx[j]], 1);
}

// fused small-array decode: 13 jobs in one launch
struct DJob { const void* src; float* dst; int n; };
struct DJobs { DJob j[13]; };
__global__ void decode_many(DJobs jobs, const int* __restrict__ flags){
    const DJob J = jobs.j[blockIdx.x];
    int fbf = flags[0];
    for (int i = threadIdx.x; i < J.n; i += 256)
        J.dst[i] = loadF(J.src, (size_t)i, fbf);
}

// -------- fused-pair split GEMM (round-7 structure): C[M x 512] = A * Bt^T --------
// 128x128 tile, 4 waves, BK=32 double-buffered global_load_lds + counted vmcnt.
// Variants (exactly one runs, device-gated):
//  <1,1>: bf16 A (raw feats) & bf16 weights -> Ah+Bh only, 32KB LDS, 1 MFMA/frag.
//  <0,1>: hi/lo A, bf16 weights -> 48KB LDS (round-7 main path).
//  <0,0>: f32-weight insurance.
template<int AZT, int BZ>
__global__ __launch_bounds__(256, (AZT && BZ) ? 4 : 3) void gemm_tpl(
        const void* __restrict__ A, const short* __restrict__ Alo, int aRaw,
        const short* __restrict__ Bhi, const short* __restrict__ Blo,
        float* __restrict__ C, int M, int K,
        const int* __restrict__ flags, const int* __restrict__ bLoFlag){
    const int fbf = flags[0];
    const int azr = (aRaw && fbf) ? 1 : 0;
    const int bLo = bLoFlag[0];
    if (AZT){ if (!azr || bLo) return; }
    else if (BZ){ if (azr || bLo) return; }
    else { if (!bLo) return; }
    __shared__ __align__(16) short Ah[2][128 * 32];
    __shared__ __align__(16) short Al[2][AZT ? 8 : 128 * 32];
    __shared__ __align__(16) short Bh[2][128 * 32];
    __shared__ __align__(16) short Bl[2][BZ ? 8 : 128 * 32];
    const int az   = AZT ? 1 : (BZ ? 0 : azr);
    const int aF32 = AZT ? 0 : ((aRaw && !fbf) ? 1 : 0);
    const int t = threadIdx.x;
    const int w = t >> 6, lane = t & 63;
    const int wr = w >> 1, wc = w & 1;
    const int bRow = blockIdx.x * 128;
    const int bCol = blockIdx.y * 128;
    const short* Ahp = (const short*)A;
    const float* Af  = (const float*)A;

    floatx4 acc[4][4];
    #pragma unroll
    for (int m = 0; m < 4; m++)
        #pragma unroll
        for (int n = 0; n < 4; n++) acc[m][n] = (floatx4){0.f, 0.f, 0.f, 0.f};

    auto STAGE = [&](int buf, int kk){
        #pragma unroll
        for (int iss = 0; iss < 2; iss++){
            int ci  = (iss * 4 + w) * 64 + lane;      // chunk index 0..511
            int row = ci >> 2;
            int cg  = (ci & 3) ^ (row & 3);           // pre-swizzled source chunk
            int gr = bRow + row; if (gr >= M) gr = M - 1;
            size_t ga  = (size_t)gr * K + kk + cg * 8;
            size_t gbi = (size_t)(bCol + row) * K + kk + cg * 8;
            int seg = (iss * 4 + w) * 512;            // linear LDS dest (shorts)
            if (!aF32){
                gload16(&Ahp[ga], &Ah[buf][seg]);
                if (!az) gload16(&Alo[ga], &Al[buf][seg]);
            }
            gload16(&Bhi[gbi], &Bh[buf][seg]);
            if (!BZ) gload16(&Blo[gbi], &Bl[buf][seg]);
        }
        if (aF32){
            #pragma unroll
            for (int iss = 0; iss < 2; iss++){
                int ci  = (iss * 4 + w) * 64 + lane;
                int row = ci >> 2, cl = ci & 3;
                int slot = cl ^ (row & 3);
                int gr = bRow + row; if (gr >= M) gr = M - 1;
                size_t ga = (size_t)gr * K + kk + cl * 8;
                floatx4 v0 = *(const floatx4*)&Af[ga];
                floatx4 v1 = *(const floatx4*)&Af[ga + 4];
                short8v h, l;
                #pragma unroll
                for (int j = 0; j < 4; j++){
                    short hj = f2b(v0[j]);
                    h[j] = hj; l[j] = f2b(v0[j] - b2f(hj));
                    short hk = f2b(v1[j]);
                    h[4 + j] = hk; l[4 + j] = f2b(v1[j] - b2f(hk));
                }
                *(short8v*)&Ah[buf][row * 32 + slot * 8] = h;
                *(short8v*)&Al[buf][row * 32 + slot * 8] = l;
            }
        }
    };

    const int T = K >> 5;
    STAGE(0, 0);
    int cur = 0;
    for (int kt = 0; kt < T; ++kt){
        if (kt + 1 < T) STAGE(cur ^ 1, (kt + 1) << 5);
        if (aF32){
            asm volatile("s_waitcnt vmcnt(0) lgkmcnt(0)" ::: "memory");
        } else if (kt + 1 >= T){
            asm volatile("s_waitcnt vmcnt(0)" ::: "memory");
        } else if (az){
            if (BZ) asm volatile("s_waitcnt vmcnt(4)" ::: "memory");
            else    asm volatile("s_waitcnt vmcnt(6)" ::: "memory");
        } else {
            if (BZ) asm volatile("s_waitcnt vmcnt(6)" ::: "memory");
            else    asm volatile("s_waitcnt vmcnt(8)" ::: "memory");
        }
        __builtin_amdgcn_s_barrier();
        short8v a_h[4], a_l[4], b_h[4], b_l[4];
        #pragma unroll
        for (int m = 0; m < 4; m++){
            int ar = wr * 64 + m * 16 + (lane & 15);
            int co = (((lane >> 4) ^ (ar & 3)) << 3);
            a_h[m] = *(const short8v*)&Ah[cur][ar * 32 + co];
            if (!az) a_l[m] = *(const short8v*)&Al[cur][ar * 32 + co];
        }
        #pragma unroll
        for (int n = 0; n < 4; n++){
            int br = wc * 64 + n * 16 + (lane & 15);
            int co = (((lane >> 4) ^ (br & 3)) << 3);
            b_h[n] = *(const short8v*)&Bh[cur][br * 32 + co];
            if (!BZ) b_l[n] = *(const short8v*)&Bl[cur][br * 32 + co];
        }
        #pragma unroll
        for (int m = 0; m < 4; m++)
            #pragma unroll
            for (int n = 0; n < 4; n++){
                if (!az) acc[m][n] = __builtin_amdgcn_mfma_f32_16x16x32_bf16(
                                         a_l[m], b_h[n], acc[m][n], 0, 0, 0);
                if (!BZ) acc[m][n] = __builtin_amdgcn_mfma_f32_16x16x32_bf16(
                                         a_h[m], b_l[n], acc[m][n], 0, 0, 0);
                acc[m][n] = __builtin_amdgcn_mfma_f32_16x16x32_bf16(
                                a_h[m], b_h[n], acc[m][n], 0, 0, 0);
            }
        __builtin_amdgcn_s_barrier();
        cur ^= 1;
    }
    #pragma unroll
    for (int m = 0; m < 4; m++){
        int rb = bRow + wr * 64 + m * 16 + ((lane >> 4) << 2);
        #pragma unroll
        for (int n = 0; n < 4; n++){
            int cg = bCol + wc * 64 + n * 16 + (lane & 15);
            #pragma unroll
            for (int r = 0; r < 4; r++){
                int gr = rb + r;
                if (gr < M) C[(size_t)gr * 512 + cg] = acc[m][n][r];
            }
        }
    }
}

// ------- fused per-node: scores + online softmax + aggregation + bias + relu -------
// round-5 structure; butterfly replaced by DPP waveSum; VGPR pinned <= 64.
__global__ __launch_bounds__(256, 8) void fused_agg(const float* __restrict__ PR,
        const int* __restrict__ srcS, const float* __restrict__ eaS,
        const int* __restrict__ off, const float* __restrict__ WeF,
        const float* __restrict__ attF, const float* __restrict__ bbF,
        short* __restrict__ QHi, short* __restrict__ QLo, int N){
    int node = blockIdx.x * 4 + (threadIdx.x >> 6);
    int lane = threadIdx.x & 63;
    if (node >= N) return;
    const int beg = off[node], end = off[node + 1];
    const int dd = lane << 2;
    const floatx4 xr4 = *(const floatx4*)&PR[(size_t)node * 512 + 256 + dd];
    const floatx4 we4 = *(const floatx4*)&WeF[dd];
    const floatx4 at4 = *(const floatx4*)&attF[dd];
    float m = -1e30f, ssum = 0.f;
    floatx4 a4 = (floatx4){0.f, 0.f, 0.f, 0.f};
    for (int k0 = beg; k0 < end; k0 += 8){
        floatx4 v[8]; float pp[8]; float eav[8];
        #pragma unroll
        for (int c = 0; c < 8; c++){
            int k = k0 + c; if (k >= end) k = end - 1;
            int s = srcS[k];
            eav[c] = eaS[k];
            v[c] = *(const floatx4*)&PR[(size_t)s * 512 + dd];
        }
        #pragma unroll
        for (int c = 0; c < 8; c++){
            float p = 0.f;
            #pragma unroll
            for (int j = 0; j < 4; j++){
                float tv = v[c][j] + xr4[j] + eav[c] * we4[j];
                tv = tv > 0.f ? tv : 0.2f * tv;
                p += tv * at4[j];
            }
            float ps = waveSum(p);
            pp[c] = (k0 + c < end) ? ps : -1e30f;
        }
        float pm = pp[0];
        #pragma unroll
        for (int c = 1; c < 8; c++) pm = fmaxf(pm, pp[c]);
        float newm = fmaxf(m, pm);
        float scale = __expf(m - newm);
        ssum *= scale;
        a4[0] *= scale; a4[1] *= scale; a4[2] *= scale; a4[3] *= scale;
        #pragma unroll
        for (int c = 0; c < 8; c++){
            float wgt = __expf(pp[c] - newm);
            ssum += wgt;
            a4[0] += wgt * v[c][0]; a4[1] += wgt * v[c][1];
            a4[2] += wgt * v[c][2]; a4[3] += wgt * v[c][3];
        }
        m = newm;
    }
    float inv = (end > beg) ? 1.f / ssum : 0.f;
    short4v h4, l4;
    #pragma unroll
    for (int j = 0; j < 4; j++){
        float o = fmaxf(a4[j] * inv + bbF[dd + j], 0.f);
        short h = f2b(o);
        h4[j] = h;
        l4[j] = f2b(o - b2f(h));
    }
    *(short4v*)&QHi[(size_t)node * 256 + dd] = h4;
    *(short4v*)&QLo[(size_t)node * 256 + dd] = l4;
}

// ---------------- global max pool over hi/lo activation ----------------
__global__ __launch_bounds__(256) void col_max2(const short* __restrict__ hi,
        const short* __restrict__ lo, unsigned* __restrict__ pool, int N){
    int lane = threadIdx.x & 63;
    int w = threadIdx.x >> 6;
    int dd = lane << 2;
    floatx4 mx = (floatx4){0.f, 0.f, 0.f, 0.f};
    for (int r = blockIdx.x * 4 + w; r < N; r += gridDim.x * 4){
        short4v h = *(const short4v*)&hi[(size_t)r * 256 + dd];
        short4v l = *(const short4v*)&lo[(size_t)r * 256 + dd];
        mx[0] = fmaxf(mx[0], b2f(h[0]) + b2f(l[0]));
        mx[1] = fmaxf(mx[1], b2f(h[1]) + b2f(l[1]));
        mx[2] = fmaxf(mx[2], b2f(h[2]) + b2f(l[2]));
        mx[3] = fmaxf(mx[3], b2f(h[3]) + b2f(l[3]));
    }
    atomicMax(&pool[dd + 0], __float_as_uint(mx[0]));
    atomicMax(&pool[dd + 1], __float_as_uint(mx[1]));
    atomicMax(&pool[dd + 2], __float_as_uint(mx[2]));
    atomicMax(&pool[dd + 3], __float_as_uint(mx[3]));
}

__global__ void head_kernel(const unsigned* __restrict__ pool, const float* __restrict__ Wh1F,
        const float* __restrict__ bh1F, const float* __restrict__ Wh2F,
        const float* __restrict__ bh2F, void* __restrict__ out, const int* __restrict__ flags){
    int lane = threadIdx.x;
    float acc = 0.f;
    if (lane < 10){
        acc = bh1F[lane];
        for (int d = 0; d < 256; ++d)
            acc += __uint_as_float(pool[d]) * Wh1F[d * 10 + lane];
        acc = fmaxf(acc, 0.f) * Wh2F[lane];
    }
    #pragma unroll
    for (int o = 32; o > 0; o >>= 1) acc += __shfl_xor(acc, o);
    if (lane == 0){
        float r = acc + bh2F[0];
        if (flags[0]) ((short*)out)[0] = f2b(r);
        else          ((float*)out)[0] = r;
    }
}

extern "C" void kernel_launch(void* const* d_in, const int* in_sizes, int n_in,
                              void* d_out, int out_size, void* d_ws, size_t ws_size,
                              hipStream_t stream){
    const void* feat = d_in[0];
    const void* ei   = d_in[1];
    const void* ea   = d_in[2];
    const void* Wl[3] = {d_in[3], d_in[8],  d_in[13]};
    const void* Wr[3] = {d_in[4], d_in[9],  d_in[14]};
    const void* We[3] = {d_in[5], d_in[10], d_in[15]};
    const void* at[3] = {d_in[6], d_in[11], d_in[16]};
    const void* bb[3] = {d_in[7], d_in[12], d_in[17]};
    const void* Wh1 = d_in[18];
    const void* bh1 = d_in[19];
    const void* Wh2 = d_in[20];
    const void* bh2 = d_in[21];

    const int N = in_sizes[0] / 128;
    const int E = in_sizes[1] / 2;
    const int Kin[3] = {128, 256, 256};
    const int nb = (N + 1023) / 1024;

    char* p = (char*)d_ws;
    auto alloc = [&](size_t bytes) -> void* {
        void* r = (void*)p; p += (bytes + 255) & ~(size_t)255; return r;
    };
    int*   flags   = (int*)alloc(256);
    int*   partial = (int*)alloc(256 * 4);
    int*   off   = (int*)alloc((size_t)(N + 1) * 4);
    int*   cnt   = (int*)alloc((size_t)N * 4);
    int*   fill  = (int*)alloc((size_t)N * 4);
    int*   srcS  = (int*)alloc((size_t)E * 4);
    float* eaS   = (float*)alloc((size_t)E * 4);
    float* PR    = (float*)alloc((size_t)N * 512 * 4);
    short* QHi   = (short*)alloc((size_t)N * 256 * 2);
    short* QLo   = (short*)alloc((size_t)N * 256 * 2);
    short* BtH[3]; short* BtL[3];
    for (int i = 0; i < 3; i++){
        BtH[i] = (short*)alloc((size_t)512 * Kin[i] * 2);
        BtL[i] = (short*)alloc((size_t)512 * Kin[i] * 2);
    }
    float* WeF  = (float*)alloc(3 * 256 * 4);
    float* attF = (float*)alloc(3 * 256 * 4);
    float* bbF  = (float*)alloc(3 * 256 * 4);
    float* Wh1F = (float*)alloc(2560 * 4);
    float* bh1F = (float*)alloc(16 * 4);
    float* Wh2F = (float*)alloc(16 * 4);
    float* bh2F = (float*)alloc(4 * 4);
    unsigned* pool = (unsigned*)alloc(256 * 4);
    size_t need = (size_t)(p - (char*)d_ws);

    setup_kernel<<<dim3((N + 255) / 256), dim3(256), 0, stream>>>(feat, ei, N, flags,
                                                                  cnt, fill, pool, d_out);
    if (need > ws_size){
        sentinel_kernel<<<dim3(1), dim3(1), 0, stream>>>(d_out, flags, 555.0f);
        return;
    }

    hist_kernel<<<dim3((E + 255) / 256), dim3(256), 0, stream>>>(ei, cnt, E, flags);
    scanA<<<dim3(nb), dim3(1024), 0, stream>>>(cnt, off, partial, N);
    scanB<<<dim3(1), dim3(64), 0, stream>>>(partial, off, nb, N);
    scanC<<<dim3(nb), dim3(1024), 0, stream>>>(off, partial, N);
    scatter_kernel<<<dim3((E + 255) / 256), dim3(256), 0, stream>>>(ei, ea, off, fill,
                                                                    srcS, eaS, E, flags);
    PJobs pj;
    for (int i = 0; i < 3; i++){
        pj.W[2 * i]     = Wl[i];
        pj.bhi[2 * i]   = BtH[i];
        pj.blo[2 * i]   = BtL[i];
        pj.W[2 * i + 1]   = Wr[i];
        pj.bhi[2 * i + 1] = BtH[i] + (size_t)256 * Kin[i];
        pj.blo[2 * i + 1] = BtL[i] + (size_t)256 * Kin[i];
        pj.K[2 * i] = pj.K[2 * i + 1] = Kin[i];
        pj.fidx[2 * i] = pj.fidx[2 * i + 1] = 8 + i;
    }
    prep_all<<<dim3(256, 6), dim3(256), 0, stream>>>(pj, flags);

    DJobs jobs;
    for (int i = 0; i < 3; i++){
        jobs.j[i]     = { We[i], WeF  + i * 256, 256 };
        jobs.j[3 + i] = { at[i], attF + i * 256, 256 };
        jobs.j[6 + i] = { bb[i], bbF  + i * 256, 256 };
    }
    jobs.j[9]  = { Wh1, Wh1F, 2560 };
    jobs.j[10] = { bh1, bh1F, 10 };
    jobs.j[11] = { Wh2, Wh2F, 10 };
    jobs.j[12] = { bh2, bh2F, 1 };
    decode_many<<<dim3(13), dim3(256), 0, stream>>>(jobs, flags);

    dim3 gemm_grid((N + 127) / 128, 4);
    for (int L = 0; L < 3; L++){
        const void* A = (L == 0) ? feat : (const void*)QHi;
        int aRaw = (L == 0) ? 1 : 0;
        if (L == 0){
            gemm_tpl<1,1><<<gemm_grid, dim3(256), 0, stream>>>(A, QLo, aRaw, BtH[L], BtL[L],
                                                               PR, N, Kin[L], flags, &flags[8 + L]);
            gemm_tpl<0,1><<<gemm_grid, dim3(256), 0, stream>>>(A, QLo, aRaw, BtH[L], BtL[L],
                                                               PR, N, Kin[L], flags, &flags[8 + L]);
        } else {
            gemm_tpl<0,1><<<gemm_grid, dim3(256), 0, stream>>>(A, QLo, aRaw, BtH[L], BtL[L],
                                                               PR, N, Kin[L], flags, &flags[8 + L]);
        }
        gemm_tpl<0,0><<<gemm_grid, dim3(256), 0, stream>>>(A, QLo, aRaw, BtH[L], BtL[L],
                                                           PR, N, Kin[L], flags, &flags[8 + L]);
        fused_agg<<<dim3((N + 3) / 4), dim3(256), 0, stream>>>(PR, srcS, eaS, off,
                                                               WeF + L * 256, attF + L * 256,
                                                               bbF + L * 256, QHi, QLo, N);
    }
    col_max2<<<dim3(256), dim3(256), 0, stream>>>(QHi, QLo, pool, N);
    head_kernel<<<dim3(1), dim3(64), 0, stream>>>(pool, Wh1F, bh1F, Wh2F, bh2F, d_out, flags);
    (void)n_in; (void)out_size;
}

// Round 11
// 827.956 us; speedup vs baseline: 2.2572x; 2.2572x over previous
//
#include <hip/hip_runtime.h>
#include <cstddef>
#include <cstdint>

typedef __attribute__((ext_vector_type(8))) short short8v;
typedef __attribute__((ext_vector_type(4))) short short4v;
typedef __attribute__((ext_vector_type(4))) float floatx4;

__device__ __forceinline__ float b2f(short u){
    return __uint_as_float(((unsigned)(unsigned short)u) << 16);
}
__device__ __forceinline__ short f2b(float f){
    unsigned x = __float_as_uint(f);
    unsigned r = x + 0x7FFFu + ((x >> 16) & 1u);
    return (short)(r >> 16);
}
__device__ __forceinline__ float loadF(const void* p, size_t i, int isBf16){
    return isBf16 ? b2f(((const short*)p)[i]) : ((const float*)p)[i];
}
__device__ __forceinline__ int loadI(const void* p, size_t i, int isI64){
    return isI64 ? ((const int*)p)[2 * i] : ((const int*)p)[i];
}
// async global->LDS, 16B per lane; dest = lds_base + lane*16 (wave-uniform base)
__device__ __forceinline__ void gload16(const void* g, void* l){
    __builtin_amdgcn_global_load_lds(
        (const __attribute__((address_space(1))) void*)g,
        (__attribute__((address_space(3))) void*)l, 16, 0, 0);
}

// ---- setup: zero cnt/fill/pool + dtype detect + sentinel (one launch) ----
// flags: [0]=floats-bf16 [1]=ints-i64 [8..10]=B-hasLo per layer
__global__ void setup_kernel(const void* feat, const void* ei, int N, int* flags,
                             int* cnt, int* fill, unsigned* pool, void* out){
    int gid = blockIdx.x * 256 + threadIdx.x;
    if (gid < N){ cnt[gid] = 0; fill[gid] = 0; }
    if (gid < 256) pool[gid] = 0u;
    if (blockIdx.x == 0){
        int t = threadIdx.x;
        if (t < 64){
            if (t >= 8 && t < 16) flags[t] = 0;
            const unsigned short* fs = (const unsigned short*)feat;
            int plaus = 0;
            for (int j = t; j < 128; j += 64){
                unsigned short s = fs[2 * j];
                int e = (s >> 7) & 0xFF;
                if (s == 0 || (e >= 100 && e <= 140)) plaus++;
            }
            #pragma unroll
            for (int o = 32; o > 0; o >>= 1) plaus += __shfl_xor(plaus, o);
            const int* ew = (const int*)ei;
            int zeros = 0;
            for (int j = t; j < 128; j += 64) if (ew[2 * j + 1] == 0) zeros++;
            #pragma unroll
            for (int o = 32; o > 0; o >>= 1) zeros += __shfl_xor(zeros, o);
            if (t == 0){
                flags[0] = (plaus >= 64) ? 1 : 0;
                flags[1] = (zeros >= 64) ? 1 : 0;
            }
        }
        __syncthreads();
        if (threadIdx.x == 0){
            if (flags[0]) ((short*)out)[0] = f2b(777.0f);
            else          ((float*)out)[0] = 777.0f;
        }
    }
}

__global__ void sentinel_kernel(void* out, const int* flags, float v){
    if (threadIdx.x == 0){
        if (flags[0]) ((short*)out)[0] = f2b(v);
        else          ((float*)out)[0] = v;
    }
}

__global__ void hist_kernel(const void* __restrict__ ei, int* __restrict__ cnt, int E,
                            const int* __restrict__ flags){
    int i = blockIdx.x * 256 + threadIdx.x;
    if (i < E) atomicAdd(&cnt[loadI(ei, (size_t)E + i, flags[1])], 1);
}

// ---- 3-phase scan ----
__global__ void scanA(const int* __restrict__ cnt, int* __restrict__ off,
                      int* __restrict__ partial, int N){
    __shared__ int wsum[16];
    const int t = threadIdx.x, w = t >> 6, lane = t & 63;
    int i = blockIdx.x * 1024 + t;
    int v = (i < N) ? cnt[i] : 0;
    int x = v;
    #pragma unroll
    for (int o = 1; o < 64; o <<= 1){
        int y = __shfl_up(x, o);
        if (lane >= o) x += y;
    }
    if (lane == 63) wsum[w] = x;
    __syncthreads();
    if (w == 0){
        int mv = (lane < 16) ? wsum[lane] : 0;
        int xx = mv;
        #pragma unroll
        for (int o = 1; o < 16; o <<= 1){
            int y = __shfl_up(xx, o);
            if (lane >= o) xx += y;
        }
        if (lane < 16) wsum[lane] = xx - mv;
    }
    __syncthreads();
    int incl = x + wsum[w];
    if (i < N) off[i] = incl - v;
    if (t == 1023) partial[blockIdx.x] = incl;
}

__global__ void scanB(int* __restrict__ partial, int* __restrict__ off, int nb, int N){
    int lane = threadIdx.x;
    int v = (lane < nb) ? partial[lane] : 0;
    int x = v;
    #pragma unroll
    for (int o = 1; o < 64; o <<= 1){
        int y = __shfl_up(x, o);
        if (lane >= o) x += y;
    }
    if (lane < nb) partial[lane] = x - v;
    if (lane == 63) off[N] = x;
}

__global__ void scanC(int* __restrict__ off, const int* __restrict__ partial, int N){
    int i = blockIdx.x * 1024 + threadIdx.x;
    if (i < N) off[i] += partial[blockIdx.x];
}

__global__ void scatter_kernel(const void* __restrict__ ei, const void* __restrict__ ea,
                               const int* __restrict__ off, int* __restrict__ fill,
                               int* __restrict__ srcS, float* __restrict__ eaS,
                               int E, const int* __restrict__ flags){
    int i = blockIdx.x * 256 + threadIdx.x;
    if (i >= E) return;
    int d = loadI(ei, (size_t)E + i, flags[1]);
    int pos = off[d] + atomicAdd(&fill[d], 1);
    srcS[pos] = loadI(ei, (size_t)i, flags[1]);
    eaS[pos] = loadF(ea, (size_t)i, flags[0]);
}

// ---- all six W [K x 256] -> Bt hi/lo in one launch; grid (256, 6) ----
struct PJobs { const void* W[6]; short* bhi[6]; short* blo[6]; int K[6]; int fidx[6]; };
__global__ void prep_all(PJobs J, int* __restrict__ flags){
    int j = blockIdx.y;
    int K = J.K[j];
    if (blockIdx.x >= K) return;
    int idx = blockIdx.x * 256 + threadIdx.x;
    int k = idx >> 8, c = idx & 255;
    float v = loadF(J.W[j], idx, flags[0]);
    short h = f2b(v);
    short l = f2b(v - b2f(h));
    J.bhi[j][(size_t)c * K + k] = h;
    J.blo[j][(size_t)c * K + k] = l;
    if (__ballot(l != 0) != 0ull && (threadIdx.x & 63) == 0) atomicOr(&flags[J.fidx[j]], 1);
}

// fused small-array decode: 13 jobs in one launch
struct DJob { const void* src; float* dst; int n; };
struct DJobs { DJob j[13]; };
__global__ void decode_many(DJobs jobs, const int* __restrict__ flags){
    const DJob J = jobs.j[blockIdx.x];
    int fbf = flags[0];
    for (int i = threadIdx.x; i < J.n; i += 256)
        J.dst[i] = loadF(J.src, (size_t)i, fbf);
}

// -------- fused-pair split GEMM (round-7 structure): C[M x 512] = A * Bt^T --------
// 128x128 tile, 4 waves, BK=32 double-buffered global_load_lds + counted vmcnt.
// Variants (exactly one runs, device-gated):
//  <1,1>: bf16 A (raw feats) & bf16 weights -> Ah+Bh only, 32KB LDS, 1 MFMA/frag.
//  <0,1>: hi/lo A, bf16 weights -> 48KB LDS (round-7 main path).
//  <0,0>: f32-weight insurance.
template<int AZT, int BZ>
__global__ __launch_bounds__(256, (AZT && BZ) ? 4 : 3) void gemm_tpl(
        const void* __restrict__ A, const short* __restrict__ Alo, int aRaw,
        const short* __restrict__ Bhi, const short* __restrict__ Blo,
        float* __restrict__ C, int M, int K,
        const int* __restrict__ flags, const int* __restrict__ bLoFlag){
    const int fbf = flags[0];
    const int azr = (aRaw && fbf) ? 1 : 0;
    const int bLo = bLoFlag[0];
    if (AZT){ if (!azr || bLo) return; }
    else if (BZ){ if (azr || bLo) return; }
    else { if (!bLo) return; }
    __shared__ __align__(16) short Ah[2][128 * 32];
    __shared__ __align__(16) short Al[2][AZT ? 8 : 128 * 32];
    __shared__ __align__(16) short Bh[2][128 * 32];
    __shared__ __align__(16) short Bl[2][BZ ? 8 : 128 * 32];
    const int az   = AZT ? 1 : (BZ ? 0 : azr);
    const int aF32 = AZT ? 0 : ((aRaw && !fbf) ? 1 : 0);
    const int t = threadIdx.x;
    const int w = t >> 6, lane = t & 63;
    const int wr = w >> 1, wc = w & 1;
    const int bRow = blockIdx.x * 128;
    const int bCol = blockIdx.y * 128;
    const short* Ahp = (const short*)A;
    const float* Af  = (const float*)A;

    floatx4 acc[4][4];
    #pragma unroll
    for (int m = 0; m < 4; m++)
        #pragma unroll
        for (int n = 0; n < 4; n++) acc[m][n] = (floatx4){0.f, 0.f, 0.f, 0.f};

    auto STAGE = [&](int buf, int kk){
        #pragma unroll
        for (int iss = 0; iss < 2; iss++){
            int ci  = (iss * 4 + w) * 64 + lane;      // chunk index 0..511
            int row = ci >> 2;
            int cg  = (ci & 3) ^ (row & 3);           // pre-swizzled source chunk
            int gr = bRow + row; if (gr >= M) gr = M - 1;
            size_t ga  = (size_t)gr * K + kk + cg * 8;
            size_t gbi = (size_t)(bCol + row) * K + kk + cg * 8;
            int seg = (iss * 4 + w) * 512;            // linear LDS dest (shorts)
            if (!aF32){
                gload16(&Ahp[ga], &Ah[buf][seg]);
                if (!az) gload16(&Alo[ga], &Al[buf][seg]);
            }
            gload16(&Bhi[gbi], &Bh[buf][seg]);
            if (!BZ) gload16(&Blo[gbi], &Bl[buf][seg]);
        }
        if (aF32){
            #pragma unroll
            for (int iss = 0; iss < 2; iss++){
                int ci  = (iss * 4 + w) * 64 + lane;
                int row = ci >> 2, cl = ci & 3;
                int slot = cl ^ (row & 3);
                int gr = bRow + row; if (gr >= M) gr = M - 1;
                size_t ga = (size_t)gr * K + kk + cl * 8;
                floatx4 v0 = *(const floatx4*)&Af[ga];
                floatx4 v1 = *(const floatx4*)&Af[ga + 4];
                short8v h, l;
                #pragma unroll
                for (int j = 0; j < 4; j++){
                    short hj = f2b(v0[j]);
                    h[j] = hj; l[j] = f2b(v0[j] - b2f(hj));
                    short hk = f2b(v1[j]);
                    h[4 + j] = hk; l[4 + j] = f2b(v1[j] - b2f(hk));
                }
                *(short8v*)&Ah[buf][row * 32 + slot * 8] = h;
                *(short8v*)&Al[buf][row * 32 + slot * 8] = l;
            }
        }
    };

    const int T = K >> 5;
    STAGE(0, 0);
    int cur = 0;
    for (int kt = 0; kt < T; ++kt){
        if (kt + 1 < T) STAGE(cur ^ 1, (kt + 1) << 5);
        if (aF32){
            asm volatile("s_waitcnt vmcnt(0) lgkmcnt(0)" ::: "memory");
        } else if (kt + 1 >= T){
            asm volatile("s_waitcnt vmcnt(0)" ::: "memory");
        } else if (az){
            if (BZ) asm volatile("s_waitcnt vmcnt(4)" ::: "memory");
            else    asm volatile("s_waitcnt vmcnt(6)" ::: "memory");
        } else {
            if (BZ) asm volatile("s_waitcnt vmcnt(6)" ::: "memory");
            else    asm volatile("s_waitcnt vmcnt(8)" ::: "memory");
        }
        __builtin_amdgcn_s_barrier();
        short8v a_h[4], a_l[4], b_h[4], b_l[4];
        #pragma unroll
        for (int m = 0; m < 4; m++){
            int ar = wr * 64 + m * 16 + (lane & 15);
            int co = (((lane >> 4) ^ (ar & 3)) << 3);
            a_h[m] = *(const short8v*)&Ah[cur][ar * 32 + co];
            if (!az) a_l[m] = *(const short8v*)&Al[cur][ar * 32 + co];
        }
        #pragma unroll
        for (int n = 0; n < 4; n++){
            int br = wc * 64 + n * 16 + (lane & 15);
            int co = (((lane >> 4) ^ (br & 3)) << 3);
            b_h[n] = *(const short8v*)&Bh[cur][br * 32 + co];
            if (!BZ) b_l[n] = *(const short8v*)&Bl[cur][br * 32 + co];
        }
        #pragma unroll
        for (int m = 0; m < 4; m++)
            #pragma unroll
            for (int n = 0; n < 4; n++){
                if (!az) acc[m][n] = __builtin_amdgcn_mfma_f32_16x16x32_bf16(
                                         a_l[m], b_h[n], acc[m][n], 0, 0, 0);
                if (!BZ) acc[m][n] = __builtin_amdgcn_mfma_f32_16x16x32_bf16(
                                         a_h[m], b_l[n], acc[m][n], 0, 0, 0);
                acc[m][n] = __builtin_amdgcn_mfma_f32_16x16x32_bf16(
                                a_h[m], b_h[n], acc[m][n], 0, 0, 0);
            }
        __builtin_amdgcn_s_barrier();
        cur ^= 1;
    }
    #pragma unroll
    for (int m = 0; m < 4; m++){
        int rb = bRow + wr * 64 + m * 16 + ((lane >> 4) << 2);
        #pragma unroll
        for (int n = 0; n < 4; n++){
            int cg = bCol + wc * 64 + n * 16 + (lane & 15);
            #pragma unroll
            for (int r = 0; r < 4; r++){
                int gr = rb + r;
                if (gr < M) C[(size_t)gr * 512 + cg] = acc[m][n][r];
            }
        }
    }
}

// ------- fused per-node (round-5/7 form, 64 VGPR — exact revert, DO NOT TOUCH) -------
__global__ __launch_bounds__(256) void fused_agg(const float* __restrict__ PR,
        const int* __restrict__ srcS, const float* __restrict__ eaS,
        const int* __restrict__ off, const float* __restrict__ WeF,
        const float* __restrict__ attF, const float* __restrict__ bbF,
        short* __restrict__ QHi, short* __restrict__ QLo, int N){
    int node = blockIdx.x * 4 + (threadIdx.x >> 6);
    int lane = threadIdx.x & 63;
    if (node >= N) return;
    const int beg = off[node], end = off[node + 1];
    const int dd = lane << 2;
    const floatx4 xr4 = *(const floatx4*)&PR[(size_t)node * 512 + 256 + dd];
    const floatx4 we4 = *(const floatx4*)&WeF[dd];
    const floatx4 at4 = *(const floatx4*)&attF[dd];
    float m = -1e30f, ssum = 0.f;
    floatx4 a4 = (floatx4){0.f, 0.f, 0.f, 0.f};
    for (int k0 = beg; k0 < end; k0 += 8){
        floatx4 v[8]; float pp[8]; float eav[8];
        #pragma unroll
        for (int c = 0; c < 8; c++){
            int k = k0 + c; if (k >= end) k = end - 1;
            int s = srcS[k];
            eav[c] = eaS[k];
            v[c] = *(const floatx4*)&PR[(size_t)s * 512 + dd];
        }
        #pragma unroll
        for (int c = 0; c < 8; c++){
            float p = 0.f;
            #pragma unroll
            for (int j = 0; j < 4; j++){
                float tv = v[c][j] + xr4[j] + eav[c] * we4[j];
                tv = tv > 0.f ? tv : 0.2f * tv;
                p += tv * at4[j];
            }
            #pragma unroll
            for (int o = 32; o > 0; o >>= 1) p += __shfl_xor(p, o);
            pp[c] = (k0 + c < end) ? p : -1e30f;
        }
        float pm = pp[0];
        #pragma unroll
        for (int c = 1; c < 8; c++) pm = fmaxf(pm, pp[c]);
        float newm = fmaxf(m, pm);
        float scale = __expf(m - newm);
        ssum *= scale;
        a4[0] *= scale; a4[1] *= scale; a4[2] *= scale; a4[3] *= scale;
        #pragma unroll
        for (int c = 0; c < 8; c++){
            float wgt = __expf(pp[c] - newm);
            ssum += wgt;
            a4[0] += wgt * v[c][0]; a4[1] += wgt * v[c][1];
            a4[2] += wgt * v[c][2]; a4[3] += wgt * v[c][3];
        }
        m = newm;
    }
    float inv = (end > beg) ? 1.f / ssum : 0.f;
    short4v h4, l4;
    #pragma unroll
    for (int j = 0; j < 4; j++){
        float o = fmaxf(a4[j] * inv + bbF[dd + j], 0.f);
        short h = f2b(o);
        h4[j] = h;
        l4[j] = f2b(o - b2f(h));
    }
    *(short4v*)&QHi[(size_t)node * 256 + dd] = h4;
    *(short4v*)&QLo[(size_t)node * 256 + dd] = l4;
}

// ---------------- global max pool over hi/lo activation ----------------
__global__ __launch_bounds__(256) void col_max2(const short* __restrict__ hi,
        const short* __restrict__ lo, unsigned* __restrict__ pool, int N){
    int lane = threadIdx.x & 63;
    int w = threadIdx.x >> 6;
    int dd = lane << 2;
    floatx4 mx = (floatx4){0.f, 0.f, 0.f, 0.f};
    for (int r = blockIdx.x * 4 + w; r < N; r += gridDim.x * 4){
        short4v h = *(const short4v*)&hi[(size_t)r * 256 + dd];
        short4v l = *(const short4v*)&lo[(size_t)r * 256 + dd];
        mx[0] = fmaxf(mx[0], b2f(h[0]) + b2f(l[0]));
        mx[1] = fmaxf(mx[1], b2f(h[1]) + b2f(l[1]));
        mx[2] = fmaxf(mx[2], b2f(h[2]) + b2f(l[2]));
        mx[3] = fmaxf(mx[3], b2f(h[3]) + b2f(l[3]));
    }
    atomicMax(&pool[dd + 0], __float_as_uint(mx[0]));
    atomicMax(&pool[dd + 1], __float_as_uint(mx[1]));
    atomicMax(&pool[dd + 2], __float_as_uint(mx[2]));
    atomicMax(&pool[dd + 3], __float_as_uint(mx[3]));
}

__global__ void head_kernel(const unsigned* __restrict__ pool, const float* __restrict__ Wh1F,
        const float* __restrict__ bh1F, const float* __restrict__ Wh2F,
        const float* __restrict__ bh2F, void* __restrict__ out, const int* __restrict__ flags){
    int lane = threadIdx.x;
    float acc = 0.f;
    if (lane < 10){
        acc = bh1F[lane];
        for (int d = 0; d < 256; ++d)
            acc += __uint_as_float(pool[d]) * Wh1F[d * 10 + lane];
        acc = fmaxf(acc, 0.f) * Wh2F[lane];
    }
    #pragma unroll
    for (int o = 32; o > 0; o >>= 1) acc += __shfl_xor(acc, o);
    if (lane == 0){
        float r = acc + bh2F[0];
        if (flags[0]) ((short*)out)[0] = f2b(r);
        else          ((float*)out)[0] = r;
    }
}

extern "C" void kernel_launch(void* const* d_in, const int* in_sizes, int n_in,
                              void* d_out, int out_size, void* d_ws, size_t ws_size,
                              hipStream_t stream){
    const void* feat = d_in[0];
    const void* ei   = d_in[1];
    const void* ea   = d_in[2];
    const void* Wl[3] = {d_in[3], d_in[8],  d_in[13]};
    const void* Wr[3] = {d_in[4], d_in[9],  d_in[14]};
    const void* We[3] = {d_in[5], d_in[10], d_in[15]};
    const void* at[3] = {d_in[6], d_in[11], d_in[16]};
    const void* bb[3] = {d_in[7], d_in[12], d_in[17]};
    const void* Wh1 = d_in[18];
    const void* bh1 = d_in[19];
    const void* Wh2 = d_in[20];
    const void* bh2 = d_in[21];

    const int N = in_sizes[0] / 128;
    const int E = in_sizes[1] / 2;
    const int Kin[3] = {128, 256, 256};
    const int nb = (N + 1023) / 1024;

    char* p = (char*)d_ws;
    auto alloc = [&](size_t bytes) -> void* {
        void* r = (void*)p; p += (bytes + 255) & ~(size_t)255; return r;
    };
    int*   flags   = (int*)alloc(256);
    int*   partial = (int*)alloc(256 * 4);
    int*   off   = (int*)alloc((size_t)(N + 1) * 4);
    int*   cnt   = (int*)alloc((size_t)N * 4);
    int*   fill  = (int*)alloc((size_t)N * 4);
    int*   srcS  = (int*)alloc((size_t)E * 4);
    float* eaS   = (float*)alloc((size_t)E * 4);
    float* PR    = (float*)alloc((size_t)N * 512 * 4);
    short* QHi   = (short*)alloc((size_t)N * 256 * 2);
    short* QLo   = (short*)alloc((size_t)N * 256 * 2);
    short* BtH[3]; short* BtL[3];
    for (int i = 0; i < 3; i++){
        BtH[i] = (short*)alloc((size_t)512 * Kin[i] * 2);
        BtL[i] = (short*)alloc((size_t)512 * Kin[i] * 2);
    }
    float* WeF  = (float*)alloc(3 * 256 * 4);
    float* attF = (float*)alloc(3 * 256 * 4);
    float* bbF  = (float*)alloc(3 * 256 * 4);
    float* Wh1F = (float*)alloc(2560 * 4);
    float* bh1F = (float*)alloc(16 * 4);
    float* Wh2F = (float*)alloc(16 * 4);
    float* bh2F = (float*)alloc(4 * 4);
    unsigned* pool = (unsigned*)alloc(256 * 4);
    size_t need = (size_t)(p - (char*)d_ws);

    setup_kernel<<<dim3((N + 255) / 256), dim3(256), 0, stream>>>(feat, ei, N, flags,
                                                                  cnt, fill, pool, d_out);
    if (need > ws_size){
        sentinel_kernel<<<dim3(1), dim3(1), 0, stream>>>(d_out, flags, 555.0f);
        return;
    }

    hist_kernel<<<dim3((E + 255) / 256), dim3(256), 0, stream>>>(ei, cnt, E, flags);
    scanA<<<dim3(nb), dim3(1024), 0, stream>>>(cnt, off, partial, N);
    scanB<<<dim3(1), dim3(64), 0, stream>>>(partial, off, nb, N);
    scanC<<<dim3(nb), dim3(1024), 0, stream>>>(off, partial, N);
    scatter_kernel<<<dim3((E + 255) / 256), dim3(256), 0, stream>>>(ei, ea, off, fill,
                                                                    srcS, eaS, E, flags);
    PJobs pj;
    for (int i = 0; i < 3; i++){
        pj.W[2 * i]     = Wl[i];
        pj.bhi[2 * i]   = BtH[i];
        pj.blo[2 * i]   = BtL[i];
        pj.W[2 * i + 1]   = Wr[i];
        pj.bhi[2 * i + 1] = BtH[i] + (size_t)256 * Kin[i];
        pj.blo[2 * i + 1] = BtL[i] + (size_t)256 * Kin[i];
        pj.K[2 * i] = pj.K[2 * i + 1] = Kin[i];
        pj.fidx[2 * i] = pj.fidx[2 * i + 1] = 8 + i;
    }
    prep_all<<<dim3(256, 6), dim3(256), 0, stream>>>(pj, flags);

    DJobs jobs;
    for (int i = 0; i < 3; i++){
        jobs.j[i]     = { We[i], WeF  + i * 256, 256 };
        jobs.j[3 + i] = { at[i], attF + i * 256, 256 };
        jobs.j[6 + i] = { bb[i], bbF  + i * 256, 256 };
    }
    jobs.j[9]  = { Wh1, Wh1F, 2560 };
    jobs.j[10] = { bh1, bh1F, 10 };
    jobs.j[11] = { Wh2, Wh2F, 10 };
    jobs.j[12] = { bh2, bh2F, 1 };
    decode_many<<<dim3(13), dim3(256), 0, stream>>>(jobs, flags);

    dim3 gemm_grid((N + 127) / 128, 4);
    for (int L = 0; L < 3; L++){
        const void* A = (L == 0) ? feat : (const void*)QHi;
        int aRaw = (L == 0) ? 1 : 0;
        if (L == 0){
            gemm_tpl<1,1><<<gemm_grid, dim3(256), 0, stream>>>(A, QLo, aRaw, BtH[L], BtL[L],
                                                               PR, N, Kin[L], flags, &flags[8 + L]);
            gemm_tpl<0,1><<<gemm_grid, dim3(256), 0, stream>>>(A, QLo, aRaw, BtH[L], BtL[L],
                                                               PR, N, Kin[L], flags, &flags[8 + L]);
        } else {
            gemm_tpl<0,1><<<gemm_grid, dim3(256), 0, stream>>>(A, QLo, aRaw, BtH[L], BtL[L],
                                                               PR, N, Kin[L], flags, &flags[8 + L]);
        }
        gemm_tpl<0,0><<<gemm_grid, dim3(256), 0, stream>>>(A, QLo, aRaw, BtH[L], BtL[L],
                                                           PR, N, Kin[L], flags, &flags[8 + L]);
        fused_agg<<<dim3((N + 3) / 4), dim3(256), 0, stream>>>(PR, srcS, eaS, off,
                                                               WeF + L * 256, attF + L * 256,
                                                               bbF + L * 256, QHi, QLo, N);
    }
    col_max2<<<dim3(256), dim3(256), 0, stream>>>(QHi, QLo, pool, N);
    head_kernel<<<dim3(1), dim3(64), 0, stream>>>(pool, Wh1F, bh1F, Wh2F, bh2F, d_out, flags);
    (void)n_in; (void)out_size;
}

// Round 12
// 815.654 us; speedup vs baseline: 2.2912x; 1.0151x over previous
//
#include <hip/hip_runtime.h>
#include <cstddef>
#include <cstdint>

typedef __attribute__((ext_vector_type(8))) short short8v;
typedef __attribute__((ext_vector_type(4))) short short4v;
typedef __attribute__((ext_vector_type(4))) float floatx4;

__device__ __forceinline__ float b2f(short u){
    return __uint_as_float(((unsigned)(unsigned short)u) << 16);
}
__device__ __forceinline__ short f2b(float f){
    unsigned x = __float_as_uint(f);
    unsigned r = x + 0x7FFFu + ((x >> 16) & 1u);
    return (short)(r >> 16);
}
__device__ __forceinline__ float loadF(const void* p, size_t i, int isBf16){
    return isBf16 ? b2f(((const short*)p)[i]) : ((const float*)p)[i];
}
__device__ __forceinline__ int loadI(const void* p, size_t i, int isI64){
    return isI64 ? ((const int*)p)[2 * i] : ((const int*)p)[i];
}
// async global->LDS, 16B per lane; dest = lds_base + lane*16 (wave-uniform base)
__device__ __forceinline__ void gload16(const void* g, void* l){
    __builtin_amdgcn_global_load_lds(
        (const __attribute__((address_space(1))) void*)g,
        (__attribute__((address_space(3))) void*)l, 16, 0, 0);
}

// ---- setup: zero cnt/fill/pool + dtype detect + sentinel (one launch) ----
// flags: [0]=floats-bf16 [1]=ints-i64 [8..10]=B-hasLo per layer
__global__ void setup_kernel(const void* feat, const void* ei, int N, int* flags,
                             int* cnt, int* fill, unsigned* pool, void* out){
    int gid = blockIdx.x * 256 + threadIdx.x;
    if (gid < N){ cnt[gid] = 0; fill[gid] = 0; }
    if (gid < 256) pool[gid] = 0u;
    if (blockIdx.x == 0){
        int t = threadIdx.x;
        if (t < 64){
            if (t >= 8 && t < 16) flags[t] = 0;
            const unsigned short* fs = (const unsigned short*)feat;
            int plaus = 0;
            for (int j = t; j < 128; j += 64){
                unsigned short s = fs[2 * j];
                int e = (s >> 7) & 0xFF;
                if (s == 0 || (e >= 100 && e <= 140)) plaus++;
            }
            #pragma unroll
            for (int o = 32; o > 0; o >>= 1) plaus += __shfl_xor(plaus, o);
            const int* ew = (const int*)ei;
            int zeros = 0;
            for (int j = t; j < 128; j += 64) if (ew[2 * j + 1] == 0) zeros++;
            #pragma unroll
            for (int o = 32; o > 0; o >>= 1) zeros += __shfl_xor(zeros, o);
            if (t == 0){
                flags[0] = (plaus >= 64) ? 1 : 0;
                flags[1] = (zeros >= 64) ? 1 : 0;
            }
        }
        __syncthreads();
        if (threadIdx.x == 0){
            if (flags[0]) ((short*)out)[0] = f2b(777.0f);
            else          ((float*)out)[0] = 777.0f;
        }
    }
}

__global__ void sentinel_kernel(void* out, const int* flags, float v){
    if (threadIdx.x == 0){
        if (flags[0]) ((short*)out)[0] = f2b(v);
        else          ((float*)out)[0] = v;
    }
}

__global__ void hist_kernel(const void* __restrict__ ei, int* __restrict__ cnt, int E,
                            const int* __restrict__ flags){
    int i = blockIdx.x * 256 + threadIdx.x;
    if (i < E) atomicAdd(&cnt[loadI(ei, (size_t)E + i, flags[1])], 1);
}

// ---- 3-phase scan ----
__global__ void scanA(const int* __restrict__ cnt, int* __restrict__ off,
                      int* __restrict__ partial, int N){
    __shared__ int wsum[16];
    const int t = threadIdx.x, w = t >> 6, lane = t & 63;
    int i = blockIdx.x * 1024 + t;
    int v = (i < N) ? cnt[i] : 0;
    int x = v;
    #pragma unroll
    for (int o = 1; o < 64; o <<= 1){
        int y = __shfl_up(x, o);
        if (lane >= o) x += y;
    }
    if (lane == 63) wsum[w] = x;
    __syncthreads();
    if (w == 0){
        int mv = (lane < 16) ? wsum[lane] : 0;
        int xx = mv;
        #pragma unroll
        for (int o = 1; o < 16; o <<= 1){
            int y = __shfl_up(xx, o);
            if (lane >= o) xx += y;
        }
        if (lane < 16) wsum[lane] = xx - mv;
    }
    __syncthreads();
    int incl = x + wsum[w];
    if (i < N) off[i] = incl - v;
    if (t == 1023) partial[blockIdx.x] = incl;
}

__global__ void scanB(int* __restrict__ partial, int* __restrict__ off, int nb, int N){
    int lane = threadIdx.x;
    int v = (lane < nb) ? partial[lane] : 0;
    int x = v;
    #pragma unroll
    for (int o = 1; o < 64; o <<= 1){
        int y = __shfl_up(x, o);
        if (lane >= o) x += y;
    }
    if (lane < nb) partial[lane] = x - v;
    if (lane == 63) off[N] = x;
}

__global__ void scanC(int* __restrict__ off, const int* __restrict__ partial, int N){
    int i = blockIdx.x * 1024 + threadIdx.x;
    if (i < N) off[i] += partial[blockIdx.x];
}

__global__ void scatter_kernel(const void* __restrict__ ei, const void* __restrict__ ea,
                               const int* __restrict__ off, int* __restrict__ fill,
                               int* __restrict__ srcS, float* __restrict__ eaS,
                               int E, const int* __restrict__ flags){
    int i = blockIdx.x * 256 + threadIdx.x;
    if (i >= E) return;
    int d = loadI(ei, (size_t)E + i, flags[1]);
    int pos = off[d] + atomicAdd(&fill[d], 1);
    srcS[pos] = loadI(ei, (size_t)i, flags[1]);
    eaS[pos] = loadF(ea, (size_t)i, flags[0]);
}

// ---- all six W [K x 256] -> Bt hi/lo in one launch; grid (256, 6) ----
struct PJobs { const void* W[6]; short* bhi[6]; short* blo[6]; int K[6]; int fidx[6]; };
__global__ void prep_all(PJobs J, int* __restrict__ flags){
    int j = blockIdx.y;
    int K = J.K[j];
    if (blockIdx.x >= K) return;
    int idx = blockIdx.x * 256 + threadIdx.x;
    int k = idx >> 8, c = idx & 255;
    float v = loadF(J.W[j], idx, flags[0]);
    short h = f2b(v);
    short l = f2b(v - b2f(h));
    J.bhi[j][(size_t)c * K + k] = h;
    J.blo[j][(size_t)c * K + k] = l;
    if (__ballot(l != 0) != 0ull && (threadIdx.x & 63) == 0) atomicOr(&flags[J.fidx[j]], 1);
}

// fused small-array decode: 13 jobs in one launch
struct DJob { const void* src; float* dst; int n; };
struct DJobs { DJob j[13]; };
__global__ void decode_many(DJobs jobs, const int* __restrict__ flags){
    const DJob J = jobs.j[blockIdx.x];
    int fbf = flags[0];
    for (int i = threadIdx.x; i < J.n; i += 256)
        J.dst[i] = loadF(J.src, (size_t)i, fbf);
}

// -------- fused-pair split GEMM (round-7 structure): C[M x 512] = A * Bt^T --------
// 128x128 tile, 4 waves, BK=32 double-buffered global_load_lds + counted vmcnt.
// Variants (exactly one runs, device-gated):
//  <1,1>: bf16 A (raw feats) & bf16 weights -> Ah+Bh only, 32KB LDS, 1 MFMA/frag.
//  <0,1>: hi/lo A, bf16 weights -> 48KB LDS (round-7 main path).
//  <0,0>: f32-weight insurance.
template<int AZT, int BZ>
__global__ __launch_bounds__(256, (AZT && BZ) ? 4 : 3) void gemm_tpl(
        const void* __restrict__ A, const short* __restrict__ Alo, int aRaw,
        const short* __restrict__ Bhi, const short* __restrict__ Blo,
        float* __restrict__ C, int M, int K,
        const int* __restrict__ flags, const int* __restrict__ bLoFlag){
    const int fbf = flags[0];
    const int azr = (aRaw && fbf) ? 1 : 0;
    const int bLo = bLoFlag[0];
    if (AZT){ if (!azr || bLo) return; }
    else if (BZ){ if (azr || bLo) return; }
    else { if (!bLo) return; }
    __shared__ __align__(16) short Ah[2][128 * 32];
    __shared__ __align__(16) short Al[2][AZT ? 8 : 128 * 32];
    __shared__ __align__(16) short Bh[2][128 * 32];
    __shared__ __align__(16) short Bl[2][BZ ? 8 : 128 * 32];
    const int az   = AZT ? 1 : (BZ ? 0 : azr);
    const int aF32 = AZT ? 0 : ((aRaw && !fbf) ? 1 : 0);
    const int t = threadIdx.x;
    const int w = t >> 6, lane = t & 63;
    const int wr = w >> 1, wc = w & 1;
    const int bRow = blockIdx.x * 128;
    const int bCol = blockIdx.y * 128;
    const short* Ahp = (const short*)A;
    const float* Af  = (const float*)A;

    floatx4 acc[4][4];
    #pragma unroll
    for (int m = 0; m < 4; m++)
        #pragma unroll
        for (int n = 0; n < 4; n++) acc[m][n] = (floatx4){0.f, 0.f, 0.f, 0.f};

    auto STAGE = [&](int buf, int kk){
        #pragma unroll
        for (int iss = 0; iss < 2; iss++){
            int ci  = (iss * 4 + w) * 64 + lane;      // chunk index 0..511
            int row = ci >> 2;
            int cg  = (ci & 3) ^ (row & 3);           // pre-swizzled source chunk
            int gr = bRow + row; if (gr >= M) gr = M - 1;
            size_t ga  = (size_t)gr * K + kk + cg * 8;
            size_t gbi = (size_t)(bCol + row) * K + kk + cg * 8;
            int seg = (iss * 4 + w) * 512;            // linear LDS dest (shorts)
            if (!aF32){
                gload16(&Ahp[ga], &Ah[buf][seg]);
                if (!az) gload16(&Alo[ga], &Al[buf][seg]);
            }
            gload16(&Bhi[gbi], &Bh[buf][seg]);
            if (!BZ) gload16(&Blo[gbi], &Bl[buf][seg]);
        }
        if (aF32){
            #pragma unroll
            for (int iss = 0; iss < 2; iss++){
                int ci  = (iss * 4 + w) * 64 + lane;
                int row = ci >> 2, cl = ci & 3;
                int slot = cl ^ (row & 3);
                int gr = bRow + row; if (gr >= M) gr = M - 1;
                size_t ga = (size_t)gr * K + kk + cl * 8;
                floatx4 v0 = *(const floatx4*)&Af[ga];
                floatx4 v1 = *(const floatx4*)&Af[ga + 4];
                short8v h, l;
                #pragma unroll
                for (int j = 0; j < 4; j++){
                    short hj = f2b(v0[j]);
                    h[j] = hj; l[j] = f2b(v0[j] - b2f(hj));
                    short hk = f2b(v1[j]);
                    h[4 + j] = hk; l[4 + j] = f2b(v1[j] - b2f(hk));
                }
                *(short8v*)&Ah[buf][row * 32 + slot * 8] = h;
                *(short8v*)&Al[buf][row * 32 + slot * 8] = l;
            }
        }
    };

    const int T = K >> 5;
    STAGE(0, 0);
    int cur = 0;
    for (int kt = 0; kt < T; ++kt){
        if (kt + 1 < T) STAGE(cur ^ 1, (kt + 1) << 5);
        if (aF32){
            asm volatile("s_waitcnt vmcnt(0) lgkmcnt(0)" ::: "memory");
        } else if (kt + 1 >= T){
            asm volatile("s_waitcnt vmcnt(0)" ::: "memory");
        } else if (az){
            if (BZ) asm volatile("s_waitcnt vmcnt(4)" ::: "memory");
            else    asm volatile("s_waitcnt vmcnt(6)" ::: "memory");
        } else {
            if (BZ) asm volatile("s_waitcnt vmcnt(6)" ::: "memory");
            else    asm volatile("s_waitcnt vmcnt(8)" ::: "memory");
        }
        __builtin_amdgcn_s_barrier();
        short8v a_h[4], a_l[4], b_h[4], b_l[4];
        #pragma unroll
        for (int m = 0; m < 4; m++){
            int ar = wr * 64 + m * 16 + (lane & 15);
            int co = (((lane >> 4) ^ (ar & 3)) << 3);
            a_h[m] = *(const short8v*)&Ah[cur][ar * 32 + co];
            if (!az) a_l[m] = *(const short8v*)&Al[cur][ar * 32 + co];
        }
        #pragma unroll
        for (int n = 0; n < 4; n++){
            int br = wc * 64 + n * 16 + (lane & 15);
            int co = (((lane >> 4) ^ (br & 3)) << 3);
            b_h[n] = *(const short8v*)&Bh[cur][br * 32 + co];
            if (!BZ) b_l[n] = *(const short8v*)&Bl[cur][br * 32 + co];
        }
        #pragma unroll
        for (int m = 0; m < 4; m++)
            #pragma unroll
            for (int n = 0; n < 4; n++){
                if (!az) acc[m][n] = __builtin_amdgcn_mfma_f32_16x16x32_bf16(
                                         a_l[m], b_h[n], acc[m][n], 0, 0, 0);
                if (!BZ) acc[m][n] = __builtin_amdgcn_mfma_f32_16x16x32_bf16(
                                         a_h[m], b_l[n], acc[m][n], 0, 0, 0);
                acc[m][n] = __builtin_amdgcn_mfma_f32_16x16x32_bf16(
                                a_h[m], b_h[n], acc[m][n], 0, 0, 0);
            }
        __builtin_amdgcn_s_barrier();
        cur ^= 1;
    }
    #pragma unroll
    for (int m = 0; m < 4; m++){
        int rb = bRow + wr * 64 + m * 16 + ((lane >> 4) << 2);
        #pragma unroll
        for (int n = 0; n < 4; n++){
            int cg = bCol + wc * 64 + n * 16 + (lane & 15);
            #pragma unroll
            for (int r = 0; r < 4; r++){
                int gr = rb + r;
                if (gr < M) C[(size_t)gr * 512 + cg] = acc[m][n][r];
            }
        }
    }
}

// ------- fused per-node: full-chunk main loop (no masking) + 2-wide masked tail -------
__global__ __launch_bounds__(256) void fused_agg(const float* __restrict__ PR,
        const int* __restrict__ srcS, const float* __restrict__ eaS,
        const int* __restrict__ off, const float* __restrict__ WeF,
        const float* __restrict__ attF, const float* __restrict__ bbF,
        short* __restrict__ QHi, short* __restrict__ QLo, int N){
    int node = blockIdx.x * 4 + (threadIdx.x >> 6);
    int lane = threadIdx.x & 63;
    if (node >= N) return;
    const int beg = off[node], end = off[node + 1];
    const int dd = lane << 2;
    const floatx4 xr4 = *(const floatx4*)&PR[(size_t)node * 512 + 256 + dd];
    const floatx4 we4 = *(const floatx4*)&WeF[dd];
    const floatx4 at4 = *(const floatx4*)&attF[dd];
    float m = -1e30f, ssum = 0.f;
    floatx4 a4 = (floatx4){0.f, 0.f, 0.f, 0.f};
    int k0 = beg;
    // main loop: full chunks only — every slot valid, no clamp/mask
    for (; k0 + 8 <= end; k0 += 8){
        floatx4 v[8]; float pp[8]; float eav[8];
        #pragma unroll
        for (int c = 0; c < 8; c++){
            int s = srcS[k0 + c];
            eav[c] = eaS[k0 + c];
            v[c] = *(const floatx4*)&PR[(size_t)s * 512 + dd];
        }
        #pragma unroll
        for (int c = 0; c < 8; c++){
            float p = 0.f;
            #pragma unroll
            for (int j = 0; j < 4; j++){
                float tv = v[c][j] + xr4[j] + eav[c] * we4[j];
                tv = tv > 0.f ? tv : 0.2f * tv;
                p += tv * at4[j];
            }
            #pragma unroll
            for (int o = 32; o > 0; o >>= 1) p += __shfl_xor(p, o);
            pp[c] = p;
        }
        float pm = pp[0];
        #pragma unroll
        for (int c = 1; c < 8; c++) pm = fmaxf(pm, pp[c]);
        float newm = fmaxf(m, pm);
        float scale = __expf(m - newm);
        ssum *= scale;
        a4[0] *= scale; a4[1] *= scale; a4[2] *= scale; a4[3] *= scale;
        #pragma unroll
        for (int c = 0; c < 8; c++){
            float wgt = __expf(pp[c] - newm);
            ssum += wgt;
            a4[0] += wgt * v[c][0]; a4[1] += wgt * v[c][1];
            a4[2] += wgt * v[c][2]; a4[3] += wgt * v[c][3];
        }
        m = newm;
    }
    // tail: up to 7 edges, 2-wide masked
    for (; k0 < end; k0 += 2){
        floatx4 v[2]; float pp[2]; float eav[2];
        #pragma unroll
        for (int c = 0; c < 2; c++){
            int k = k0 + c; if (k >= end) k = end - 1;
            int s = srcS[k];
            eav[c] = eaS[k];
            v[c] = *(const floatx4*)&PR[(size_t)s * 512 + dd];
        }
        #pragma unroll
        for (int c = 0; c < 2; c++){
            float p = 0.f;
            #pragma unroll
            for (int j = 0; j < 4; j++){
                float tv = v[c][j] + xr4[j] + eav[c] * we4[j];
                tv = tv > 0.f ? tv : 0.2f * tv;
                p += tv * at4[j];
            }
            #pragma unroll
            for (int o = 32; o > 0; o >>= 1) p += __shfl_xor(p, o);
            pp[c] = (k0 + c < end) ? p : -1e30f;
        }
        float pm = fmaxf(pp[0], pp[1]);
        float newm = fmaxf(m, pm);
        float scale = __expf(m - newm);
        ssum *= scale;
        a4[0] *= scale; a4[1] *= scale; a4[2] *= scale; a4[3] *= scale;
        #pragma unroll
        for (int c = 0; c < 2; c++){
            float wgt = __expf(pp[c] - newm);
            ssum += wgt;
            a4[0] += wgt * v[c][0]; a4[1] += wgt * v[c][1];
            a4[2] += wgt * v[c][2]; a4[3] += wgt * v[c][3];
        }
        m = newm;
    }
    float inv = (end > beg) ? 1.f / ssum : 0.f;
    short4v h4, l4;
    #pragma unroll
    for (int j = 0; j < 4; j++){
        float o = fmaxf(a4[j] * inv + bbF[dd + j], 0.f);
        short h = f2b(o);
        h4[j] = h;
        l4[j] = f2b(o - b2f(h));
    }
    *(short4v*)&QHi[(size_t)node * 256 + dd] = h4;
    *(short4v*)&QLo[(size_t)node * 256 + dd] = l4;
}

// ---------------- global max pool over hi/lo activation ----------------
__global__ __launch_bounds__(256) void col_max2(const short* __restrict__ hi,
        const short* __restrict__ lo, unsigned* __restrict__ pool, int N){
    int lane = threadIdx.x & 63;
    int w = threadIdx.x >> 6;
    int dd = lane << 2;
    floatx4 mx = (floatx4){0.f, 0.f, 0.f, 0.f};
    for (int r = blockIdx.x * 4 + w; r < N; r += gridDim.x * 4){
        short4v h = *(const short4v*)&hi[(size_t)r * 256 + dd];
        short4v l = *(const short4v*)&lo[(size_t)r * 256 + dd];
        mx[0] = fmaxf(mx[0], b2f(h[0]) + b2f(l[0]));
        mx[1] = fmaxf(mx[1], b2f(h[1]) + b2f(l[1]));
        mx[2] = fmaxf(mx[2], b2f(h[2]) + b2f(l[2]));
        mx[3] = fmaxf(mx[3], b2f(h[3]) + b2f(l[3]));
    }
    atomicMax(&pool[dd + 0], __float_as_uint(mx[0]));
    atomicMax(&pool[dd + 1], __float_as_uint(mx[1]));
    atomicMax(&pool[dd + 2], __float_as_uint(mx[2]));
    atomicMax(&pool[dd + 3], __float_as_uint(mx[3]));
}

__global__ void head_kernel(const unsigned* __restrict__ pool, const float* __restrict__ Wh1F,
        const float* __restrict__ bh1F, const float* __restrict__ Wh2F,
        const float* __restrict__ bh2F, void* __restrict__ out, const int* __restrict__ flags){
    int lane = threadIdx.x;
    float acc = 0.f;
    if (lane < 10){
        acc = bh1F[lane];
        for (int d = 0; d < 256; ++d)
            acc += __uint_as_float(pool[d]) * Wh1F[d * 10 + lane];
        acc = fmaxf(acc, 0.f) * Wh2F[lane];
    }
    #pragma unroll
    for (int o = 32; o > 0; o >>= 1) acc += __shfl_xor(acc, o);
    if (lane == 0){
        float r = acc + bh2F[0];
        if (flags[0]) ((short*)out)[0] = f2b(r);
        else          ((float*)out)[0] = r;
    }
}

extern "C" void kernel_launch(void* const* d_in, const int* in_sizes, int n_in,
                              void* d_out, int out_size, void* d_ws, size_t ws_size,
                              hipStream_t stream){
    const void* feat = d_in[0];
    const void* ei   = d_in[1];
    const void* ea   = d_in[2];
    const void* Wl[3] = {d_in[3], d_in[8],  d_in[13]};
    const void* Wr[3] = {d_in[4], d_in[9],  d_in[14]};
    const void* We[3] = {d_in[5], d_in[10], d_in[15]};
    const void* at[3] = {d_in[6], d_in[11], d_in[16]};
    const void* bb[3] = {d_in[7], d_in[12], d_in[17]};
    const void* Wh1 = d_in[18];
    const void* bh1 = d_in[19];
    const void* Wh2 = d_in[20];
    const void* bh2 = d_in[21];

    const int N = in_sizes[0] / 128;
    const int E = in_sizes[1] / 2;
    const int Kin[3] = {128, 256, 256};
    const int nb = (N + 1023) / 1024;

    char* p = (char*)d_ws;
    auto alloc = [&](size_t bytes) -> void* {
        void* r = (void*)p; p += (bytes + 255) & ~(size_t)255; return r;
    };
    int*   flags   = (int*)alloc(256);
    int*   partial = (int*)alloc(256 * 4);
    int*   off   = (int*)alloc((size_t)(N + 1) * 4);
    int*   cnt   = (int*)alloc((size_t)N * 4);
    int*   fill  = (int*)alloc((size_t)N * 4);
    int*   srcS  = (int*)alloc((size_t)E * 4);
    float* eaS   = (float*)alloc((size_t)E * 4);
    float* PR    = (float*)alloc((size_t)N * 512 * 4);
    short* QHi   = (short*)alloc((size_t)N * 256 * 2);
    short* QLo   = (short*)alloc((size_t)N * 256 * 2);
    short* BtH[3]; short* BtL[3];
    for (int i = 0; i < 3; i++){
        BtH[i] = (short*)alloc((size_t)512 * Kin[i] * 2);
        BtL[i] = (short*)alloc((size_t)512 * Kin[i] * 2);
    }
    float* WeF  = (float*)alloc(3 * 256 * 4);
    float* attF = (float*)alloc(3 * 256 * 4);
    float* bbF  = (float*)alloc(3 * 256 * 4);
    float* Wh1F = (float*)alloc(2560 * 4);
    float* bh1F = (float*)alloc(16 * 4);
    float* Wh2F = (float*)alloc(16 * 4);
    float* bh2F = (float*)alloc(4 * 4);
    unsigned* pool = (unsigned*)alloc(256 * 4);
    size_t need = (size_t)(p - (char*)d_ws);

    setup_kernel<<<dim3((N + 255) / 256), dim3(256), 0, stream>>>(feat, ei, N, flags,
                                                                  cnt, fill, pool, d_out);
    if (need > ws_size){
        sentinel_kernel<<<dim3(1), dim3(1), 0, stream>>>(d_out, flags, 555.0f);
        return;
    }

    hist_kernel<<<dim3((E + 255) / 256), dim3(256), 0, stream>>>(ei, cnt, E, flags);
    scanA<<<dim3(nb), dim3(1024), 0, stream>>>(cnt, off, partial, N);
    scanB<<<dim3(1), dim3(64), 0, stream>>>(partial, off, nb, N);
    scanC<<<dim3(nb), dim3(1024), 0, stream>>>(off, partial, N);
    scatter_kernel<<<dim3((E + 255) / 256), dim3(256), 0, stream>>>(ei, ea, off, fill,
                                                                    srcS, eaS, E, flags);
    PJobs pj;
    for (int i = 0; i < 3; i++){
        pj.W[2 * i]     = Wl[i];
        pj.bhi[2 * i]   = BtH[i];
        pj.blo[2 * i]   = BtL[i];
        pj.W[2 * i + 1]   = Wr[i];
        pj.bhi[2 * i + 1] = BtH[i] + (size_t)256 * Kin[i];
        pj.blo[2 * i + 1] = BtL[i] + (size_t)256 * Kin[i];
        pj.K[2 * i] = pj.K[2 * i + 1] = Kin[i];
        pj.fidx[2 * i] = pj.fidx[2 * i + 1] = 8 + i;
    }
    prep_all<<<dim3(256, 6), dim3(256), 0, stream>>>(pj, flags);

    DJobs jobs;
    for (int i = 0; i < 3; i++){
        jobs.j[i]     = { We[i], WeF  + i * 256, 256 };
        jobs.j[3 + i] = { at[i], attF + i * 256, 256 };
        jobs.j[6 + i] = { bb[i], bbF  + i * 256, 256 };
    }
    jobs.j[9]  = { Wh1, Wh1F, 2560 };
    jobs.j[10] = { bh1, bh1F, 10 };
    jobs.j[11] = { Wh2, Wh2F, 10 };
    jobs.j[12] = { bh2, bh2F, 1 };
    decode_many<<<dim3(13), dim3(256), 0, stream>>>(jobs, flags);

    dim3 gemm_grid((N + 127) / 128, 4);
    for (int L = 0; L < 3; L++){
        const void* A = (L == 0) ? feat : (const void*)QHi;
        int aRaw = (L == 0) ? 1 : 0;
        if (L == 0){
            gemm_tpl<1,1><<<gemm_grid, dim3(256), 0, stream>>>(A, QLo, aRaw, BtH[L], BtL[L],
                                                               PR, N, Kin[L], flags, &flags[8 + L]);
            gemm_tpl<0,1><<<gemm_grid, dim3(256), 0, stream>>>(A, QLo, aRaw, BtH[L], BtL[L],
                                                               PR, N, Kin[L], flags, &flags[8 + L]);
        } else {
            gemm_tpl<0,1><<<gemm_grid, dim3(256), 0, stream>>>(A, QLo, aRaw, BtH[L], BtL[L],
                                                               PR, N, Kin[L], flags, &flags[8 + L]);
        }
        gemm_tpl<0,0><<<gemm_grid, dim3(256), 0, stream>>>(A, QLo, aRaw, BtH[L], BtL[L],
                                                           PR, N, Kin[L], flags, &flags[8 + L]);
        fused_agg<<<dim3((N + 3) / 4), dim3(256), 0, stream>>>(PR, srcS, eaS, off,
                                                               WeF + L * 256, attF + L * 256,
                                                               bbF + L * 256, QHi, QLo, N);
    }
    col_max2<<<dim3(256), dim3(256), 0, stream>>>(QHi, QLo, pool, N);
    head_kernel<<<dim3(1), dim3(64), 0, stream>>>(pool, Wh1F, bh1F, Wh2F, bh2F, d_out, flags);
    (void)n_in; (void)out_size;
}

// Round 13
// 794.217 us; speedup vs baseline: 2.3531x; 1.0270x over previous
//
#include <hip/hip_runtime.h>
#include <cstddef>
#include <cstdint>

typedef __attribute__((ext_vector_type(8))) short short8v;
typedef __attribute__((ext_vector_type(4))) short short4v;
typedef __attribute__((ext_vector_type(4))) float floatx4;

__device__ __forceinline__ float b2f(short u){
    return __uint_as_float(((unsigned)(unsigned short)u) << 16);
}
__device__ __forceinline__ short f2b(float f){
    unsigned x = __float_as_uint(f);
    unsigned r = x + 0x7FFFu + ((x >> 16) & 1u);
    return (short)(r >> 16);
}
__device__ __forceinline__ float loadF(const void* p, size_t i, int isBf16){
    return isBf16 ? b2f(((const short*)p)[i]) : ((const float*)p)[i];
}
__device__ __forceinline__ int loadI(const void* p, size_t i, int isI64){
    return isI64 ? ((const int*)p)[2 * i] : ((const int*)p)[i];
}
// async global->LDS, 16B per lane; dest = lds_base + lane*16 (wave-uniform base)
__device__ __forceinline__ void gload16(const void* g, void* l){
    __builtin_amdgcn_global_load_lds(
        (const __attribute__((address_space(1))) void*)g,
        (__attribute__((address_space(3))) void*)l, 16, 0, 0);
}

// ---- setup: zero cnt/fill/pool + dtype detect + sentinel (one launch) ----
// flags: [0]=floats-bf16 [1]=ints-i64 [8..10]=B-hasLo per layer
__global__ void setup_kernel(const void* feat, const void* ei, int N, int* flags,
                             int* cnt, int* fill, unsigned* pool, void* out){
    int gid = blockIdx.x * 256 + threadIdx.x;
    if (gid < N){ cnt[gid] = 0; fill[gid] = 0; }
    if (gid < 256) pool[gid] = 0u;
    if (blockIdx.x == 0){
        int t = threadIdx.x;
        if (t < 64){
            if (t >= 8 && t < 16) flags[t] = 0;
            const unsigned short* fs = (const unsigned short*)feat;
            int plaus = 0;
            for (int j = t; j < 128; j += 64){
                unsigned short s = fs[2 * j];
                int e = (s >> 7) & 0xFF;
                if (s == 0 || (e >= 100 && e <= 140)) plaus++;
            }
            #pragma unroll
            for (int o = 32; o > 0; o >>= 1) plaus += __shfl_xor(plaus, o);
            const int* ew = (const int*)ei;
            int zeros = 0;
            for (int j = t; j < 128; j += 64) if (ew[2 * j + 1] == 0) zeros++;
            #pragma unroll
            for (int o = 32; o > 0; o >>= 1) zeros += __shfl_xor(zeros, o);
            if (t == 0){
                flags[0] = (plaus >= 64) ? 1 : 0;
                flags[1] = (zeros >= 64) ? 1 : 0;
            }
        }
        __syncthreads();
        if (threadIdx.x == 0){
            if (flags[0]) ((short*)out)[0] = f2b(777.0f);
            else          ((float*)out)[0] = 777.0f;
        }
    }
}

__global__ void sentinel_kernel(void* out, const int* flags, float v){
    if (threadIdx.x == 0){
        if (flags[0]) ((short*)out)[0] = f2b(v);
        else          ((float*)out)[0] = v;
    }
}

__global__ void hist_kernel(const void* __restrict__ ei, int* __restrict__ cnt, int E,
                            const int* __restrict__ flags){
    int i = blockIdx.x * 256 + threadIdx.x;
    if (i < E) atomicAdd(&cnt[loadI(ei, (size_t)E + i, flags[1])], 1);
}

// ---- 3-phase scan ----
__global__ void scanA(const int* __restrict__ cnt, int* __restrict__ off,
                      int* __restrict__ partial, int N){
    __shared__ int wsum[16];
    const int t = threadIdx.x, w = t >> 6, lane = t & 63;
    int i = blockIdx.x * 1024 + t;
    int v = (i < N) ? cnt[i] : 0;
    int x = v;
    #pragma unroll
    for (int o = 1; o < 64; o <<= 1){
        int y = __shfl_up(x, o);
        if (lane >= o) x += y;
    }
    if (lane == 63) wsum[w] = x;
    __syncthreads();
    if (w == 0){
        int mv = (lane < 16) ? wsum[lane] : 0;
        int xx = mv;
        #pragma unroll
        for (int o = 1; o < 16; o <<= 1){
            int y = __shfl_up(xx, o);
            if (lane >= o) xx += y;
        }
        if (lane < 16) wsum[lane] = xx - mv;
    }
    __syncthreads();
    int incl = x + wsum[w];
    if (i < N) off[i] = incl - v;
    if (t == 1023) partial[blockIdx.x] = incl;
}

__global__ void scanB(int* __restrict__ partial, int* __restrict__ off, int nb, int N){
    int lane = threadIdx.x;
    int v = (lane < nb) ? partial[lane] : 0;
    int x = v;
    #pragma unroll
    for (int o = 1; o < 64; o <<= 1){
        int y = __shfl_up(x, o);
        if (lane >= o) x += y;
    }
    if (lane < nb) partial[lane] = x - v;
    if (lane == 63) off[N] = x;
}

__global__ void scanC(int* __restrict__ off, const int* __restrict__ partial, int N){
    int i = blockIdx.x * 1024 + threadIdx.x;
    if (i < N) off[i] += partial[blockIdx.x];
}

__global__ void scatter_kernel(const void* __restrict__ ei, const void* __restrict__ ea,
                               const int* __restrict__ off, int* __restrict__ fill,
                               int* __restrict__ srcS, float* __restrict__ eaS,
                               int E, const int* __restrict__ flags){
    int i = blockIdx.x * 256 + threadIdx.x;
    if (i >= E) return;
    int d = loadI(ei, (size_t)E + i, flags[1]);
    int pos = off[d] + atomicAdd(&fill[d], 1);
    srcS[pos] = loadI(ei, (size_t)i, flags[1]);
    eaS[pos] = loadF(ea, (size_t)i, flags[0]);
}

// ---- all six W [K x 256] -> Bt hi/lo in one launch; grid (256, 6) ----
struct PJobs { const void* W[6]; short* bhi[6]; short* blo[6]; int K[6]; int fidx[6]; };
__global__ void prep_all(PJobs J, int* __restrict__ flags){
    int j = blockIdx.y;
    int K = J.K[j];
    if (blockIdx.x >= K) return;
    int idx = blockIdx.x * 256 + threadIdx.x;
    int k = idx >> 8, c = idx & 255;
    float v = loadF(J.W[j], idx, flags[0]);
    short h = f2b(v);
    short l = f2b(v - b2f(h));
    J.bhi[j][(size_t)c * K + k] = h;
    J.blo[j][(size_t)c * K + k] = l;
    if (__ballot(l != 0) != 0ull && (threadIdx.x & 63) == 0) atomicOr(&flags[J.fidx[j]], 1);
}

// fused small-array decode: 13 jobs in one launch
struct DJob { const void* src; float* dst; int n; };
struct DJobs { DJob j[13]; };
__global__ void decode_many(DJobs jobs, const int* __restrict__ flags){
    const DJob J = jobs.j[blockIdx.x];
    int fbf = flags[0];
    for (int i = threadIdx.x; i < J.n; i += 256)
        J.dst[i] = loadF(J.src, (size_t)i, fbf);
}

// -------- fused-pair split GEMM (round-7 structure + XCD-chunked tile swizzle) --------
// 128x128 tile, 4 waves, BK=32 double-buffered global_load_lds + counted vmcnt.
// Tile swizzle (T1/m204): hardware round-robins dispatch ids over 8 XCDs; the bijective
// chunked map gives each XCD ~nwg/8 CONSECUTIVE tiles in row-major (row,col) order, so
// one A row-stripe's 4 column-tiles run on the same XCD -> A staged from L2, not L3/HBM.
template<int AZT, int BZ>
__global__ __launch_bounds__(256, (AZT && BZ) ? 4 : 3) void gemm_tpl(
        const void* __restrict__ A, const short* __restrict__ Alo, int aRaw,
        const short* __restrict__ Bhi, const short* __restrict__ Blo,
        float* __restrict__ C, int M, int K,
        const int* __restrict__ flags, const int* __restrict__ bLoFlag){
    const int fbf = flags[0];
    const int azr = (aRaw && fbf) ? 1 : 0;
    const int bLo = bLoFlag[0];
    if (AZT){ if (!azr || bLo) return; }
    else if (BZ){ if (azr || bLo) return; }
    else { if (!bLo) return; }
    __shared__ __align__(16) short Ah[2][128 * 32];
    __shared__ __align__(16) short Al[2][AZT ? 8 : 128 * 32];
    __shared__ __align__(16) short Bh[2][128 * 32];
    __shared__ __align__(16) short Bl[2][BZ ? 8 : 128 * 32];
    const int az   = AZT ? 1 : (BZ ? 0 : azr);
    const int aF32 = AZT ? 0 : ((aRaw && !fbf) ? 1 : 0);
    const int t = threadIdx.x;
    const int w = t >> 6, lane = t & 63;
    const int wr = w >> 1, wc = w & 1;
    // ---- XCD-chunked bijective tile swizzle (m204) ----
    const int nwg = gridDim.x * gridDim.y;
    const int l   = blockIdx.y * gridDim.x + blockIdx.x;   // dispatch order
    const int q = nwg >> 3, r = nwg & 7;
    const int x8 = l & 7, pos = l >> 3;
    const int wgid = (x8 < r ? x8 * (q + 1) : r * (q + 1) + (x8 - r) * q) + pos;
    const int bRow = (wgid >> 2) * 128;                    // row-major tiles, 4 cols
    const int bCol = (wgid & 3) * 128;
    const short* Ahp = (const short*)A;
    const float* Af  = (const float*)A;

    floatx4 acc[4][4];
    #pragma unroll
    for (int m = 0; m < 4; m++)
        #pragma unroll
        for (int n = 0; n < 4; n++) acc[m][n] = (floatx4){0.f, 0.f, 0.f, 0.f};

    auto STAGE = [&](int buf, int kk){
        #pragma unroll
        for (int iss = 0; iss < 2; iss++){
            int ci  = (iss * 4 + w) * 64 + lane;      // chunk index 0..511
            int row = ci >> 2;
            int cg  = (ci & 3) ^ (row & 3);           // pre-swizzled source chunk
            int gr = bRow + row; if (gr >= M) gr = M - 1;
            size_t ga  = (size_t)gr * K + kk + cg * 8;
            size_t gbi = (size_t)(bCol + row) * K + kk + cg * 8;
            int seg = (iss * 4 + w) * 512;            // linear LDS dest (shorts)
            if (!aF32){
                gload16(&Ahp[ga], &Ah[buf][seg]);
                if (!az) gload16(&Alo[ga], &Al[buf][seg]);
            }
            gload16(&Bhi[gbi], &Bh[buf][seg]);
            if (!BZ) gload16(&Blo[gbi], &Bl[buf][seg]);
        }
        if (aF32){
            #pragma unroll
            for (int iss = 0; iss < 2; iss++){
                int ci  = (iss * 4 + w) * 64 + lane;
                int row = ci >> 2, cl = ci & 3;
                int slot = cl ^ (row & 3);
                int gr = bRow + row; if (gr >= M) gr = M - 1;
                size_t ga = (size_t)gr * K + kk + cl * 8;
                floatx4 v0 = *(const floatx4*)&Af[ga];
                floatx4 v1 = *(const floatx4*)&Af[ga + 4];
                short8v h, l2;
                #pragma unroll
                for (int j = 0; j < 4; j++){
                    short hj = f2b(v0[j]);
                    h[j] = hj; l2[j] = f2b(v0[j] - b2f(hj));
                    short hk = f2b(v1[j]);
                    h[4 + j] = hk; l2[4 + j] = f2b(v1[j] - b2f(hk));
                }
                *(short8v*)&Ah[buf][row * 32 + slot * 8] = h;
                *(short8v*)&Al[buf][row * 32 + slot * 8] = l2;
            }
        }
    };

    const int T = K >> 5;
    STAGE(0, 0);
    int cur = 0;
    for (int kt = 0; kt < T; ++kt){
        if (kt + 1 < T) STAGE(cur ^ 1, (kt + 1) << 5);
        if (aF32){
            asm volatile("s_waitcnt vmcnt(0) lgkmcnt(0)" ::: "memory");
        } else if (kt + 1 >= T){
            asm volatile("s_waitcnt vmcnt(0)" ::: "memory");
        } else if (az){
            if (BZ) asm volatile("s_waitcnt vmcnt(4)" ::: "memory");
            else    asm volatile("s_waitcnt vmcnt(6)" ::: "memory");
        } else {
            if (BZ) asm volatile("s_waitcnt vmcnt(6)" ::: "memory");
            else    asm volatile("s_waitcnt vmcnt(8)" ::: "memory");
        }
        __builtin_amdgcn_s_barrier();
        short8v a_h[4], a_l[4], b_h[4], b_l[4];
        #pragma unroll
        for (int m = 0; m < 4; m++){
            int ar = wr * 64 + m * 16 + (lane & 15);
            int co = (((lane >> 4) ^ (ar & 3)) << 3);
            a_h[m] = *(const short8v*)&Ah[cur][ar * 32 + co];
            if (!az) a_l[m] = *(const short8v*)&Al[cur][ar * 32 + co];
        }
        #pragma unroll
        for (int n = 0; n < 4; n++){
            int br = wc * 64 + n * 16 + (lane & 15);
            int co = (((lane >> 4) ^ (br & 3)) << 3);
            b_h[n] = *(const short8v*)&Bh[cur][br * 32 + co];
            if (!BZ) b_l[n] = *(const short8v*)&Bl[cur][br * 32 + co];
        }
        #pragma unroll
        for (int m = 0; m < 4; m++)
            #pragma unroll
            for (int n = 0; n < 4; n++){
                if (!az) acc[m][n] = __builtin_amdgcn_mfma_f32_16x16x32_bf16(
                                         a_l[m], b_h[n], acc[m][n], 0, 0, 0);
                if (!BZ) acc[m][n] = __builtin_amdgcn_mfma_f32_16x16x32_bf16(
                                         a_h[m], b_l[n], acc[m][n], 0, 0, 0);
                acc[m][n] = __builtin_amdgcn_mfma_f32_16x16x32_bf16(
                                a_h[m], b_h[n], acc[m][n], 0, 0, 0);
            }
        __builtin_amdgcn_s_barrier();
        cur ^= 1;
    }
    #pragma unroll
    for (int m = 0; m < 4; m++){
        int rb = bRow + wr * 64 + m * 16 + ((lane >> 4) << 2);
        #pragma unroll
        for (int n = 0; n < 4; n++){
            int cg = bCol + wc * 64 + n * 16 + (lane & 15);
            #pragma unroll
            for (int rr = 0; rr < 4; rr++){
                int gr = rb + rr;
                if (gr < M) C[(size_t)gr * 512 + cg] = acc[m][n][rr];
            }
        }
    }
}

// ------- fused per-node: full-chunk main loop (no masking) + 2-wide masked tail -------
__global__ __launch_bounds__(256) void fused_agg(const float* __restrict__ PR,
        const int* __restrict__ srcS, const float* __restrict__ eaS,
        const int* __restrict__ off, const float* __restrict__ WeF,
        const float* __restrict__ attF, const float* __restrict__ bbF,
        short* __restrict__ QHi, short* __restrict__ QLo, int N){
    int node = blockIdx.x * 4 + (threadIdx.x >> 6);
    int lane = threadIdx.x & 63;
    if (node >= N) return;
    const int beg = off[node], end = off[node + 1];
    const int dd = lane << 2;
    const floatx4 xr4 = *(const floatx4*)&PR[(size_t)node * 512 + 256 + dd];
    const floatx4 we4 = *(const floatx4*)&WeF[dd];
    const floatx4 at4 = *(const floatx4*)&attF[dd];
    float m = -1e30f, ssum = 0.f;
    floatx4 a4 = (floatx4){0.f, 0.f, 0.f, 0.f};
    int k0 = beg;
    // main loop: full chunks only — every slot valid, no clamp/mask
    for (; k0 + 8 <= end; k0 += 8){
        floatx4 v[8]; float pp[8]; float eav[8];
        #pragma unroll
        for (int c = 0; c < 8; c++){
            int s = srcS[k0 + c];
            eav[c] = eaS[k0 + c];
            v[c] = *(const floatx4*)&PR[(size_t)s * 512 + dd];
        }
        #pragma unroll
        for (int c = 0; c < 8; c++){
            float p = 0.f;
            #pragma unroll
            for (int j = 0; j < 4; j++){
                float tv = v[c][j] + xr4[j] + eav[c] * we4[j];
                tv = tv > 0.f ? tv : 0.2f * tv;
                p += tv * at4[j];
            }
            #pragma unroll
            for (int o = 32; o > 0; o >>= 1) p += __shfl_xor(p, o);
            pp[c] = p;
        }
        float pm = pp[0];
        #pragma unroll
        for (int c = 1; c < 8; c++) pm = fmaxf(pm, pp[c]);
        float newm = fmaxf(m, pm);
        float scale = __expf(m - newm);
        ssum *= scale;
        a4[0] *= scale; a4[1] *= scale; a4[2] *= scale; a4[3] *= scale;
        #pragma unroll
        for (int c = 0; c < 8; c++){
            float wgt = __expf(pp[c] - newm);
            ssum += wgt;
            a4[0] += wgt * v[c][0]; a4[1] += wgt * v[c][1];
            a4[2] += wgt * v[c][2]; a4[3] += wgt * v[c][3];
        }
        m = newm;
    }
    // tail: up to 7 edges, 2-wide masked
    for (; k0 < end; k0 += 2){
        floatx4 v[2]; float pp[2]; float eav[2];
        #pragma unroll
        for (int c = 0; c < 2; c++){
            int k = k0 + c; if (k >= end) k = end - 1;
            int s = srcS[k];
            eav[c] = eaS[k];
            v[c] = *(const floatx4*)&PR[(size_t)s * 512 + dd];
        }
        #pragma unroll
        for (int c = 0; c < 2; c++){
            float p = 0.f;
            #pragma unroll
            for (int j = 0; j < 4; j++){
                float tv = v[c][j] + xr4[j] + eav[c] * we4[j];
                tv = tv > 0.f ? tv : 0.2f * tv;
                p += tv * at4[j];
            }
            #pragma unroll
            for (int o = 32; o > 0; o >>= 1) p += __shfl_xor(p, o);
            pp[c] = (k0 + c < end) ? p : -1e30f;
        }
        float pm = fmaxf(pp[0], pp[1]);
        float newm = fmaxf(m, pm);
        float scale = __expf(m - newm);
        ssum *= scale;
        a4[0] *= scale; a4[1] *= scale; a4[2] *= scale; a4[3] *= scale;
        #pragma unroll
        for (int c = 0; c < 2; c++){
            float wgt = __expf(pp[c] - newm);
            ssum += wgt;
            a4[0] += wgt * v[c][0]; a4[1] += wgt * v[c][1];
            a4[2] += wgt * v[c][2]; a4[3] += wgt * v[c][3];
        }
        m = newm;
    }
    float inv = (end > beg) ? 1.f / ssum : 0.f;
    short4v h4, l4;
    #pragma unroll
    for (int j = 0; j < 4; j++){
        float o = fmaxf(a4[j] * inv + bbF[dd + j], 0.f);
        short h = f2b(o);
        h4[j] = h;
        l4[j] = f2b(o - b2f(h));
    }
    *(short4v*)&QHi[(size_t)node * 256 + dd] = h4;
    *(short4v*)&QLo[(size_t)node * 256 + dd] = l4;
}

// ---------------- global max pool over hi/lo activation ----------------
__global__ __launch_bounds__(256) void col_max2(const short* __restrict__ hi,
        const short* __restrict__ lo, unsigned* __restrict__ pool, int N){
    int lane = threadIdx.x & 63;
    int w = threadIdx.x >> 6;
    int dd = lane << 2;
    floatx4 mx = (floatx4){0.f, 0.f, 0.f, 0.f};
    for (int r = blockIdx.x * 4 + w; r < N; r += gridDim.x * 4){
        short4v h = *(const short4v*)&hi[(size_t)r * 256 + dd];
        short4v l = *(const short4v*)&lo[(size_t)r * 256 + dd];
        mx[0] = fmaxf(mx[0], b2f(h[0]) + b2f(l[0]));
        mx[1] = fmaxf(mx[1], b2f(h[1]) + b2f(l[1]));
        mx[2] = fmaxf(mx[2], b2f(h[2]) + b2f(l[2]));
        mx[3] = fmaxf(mx[3], b2f(h[3]) + b2f(l[3]));
    }
    atomicMax(&pool[dd + 0], __float_as_uint(mx[0]));
    atomicMax(&pool[dd + 1], __float_as_uint(mx[1]));
    atomicMax(&pool[dd + 2], __float_as_uint(mx[2]));
    atomicMax(&pool[dd + 3], __float_as_uint(mx[3]));
}

__global__ void head_kernel(const unsigned* __restrict__ pool, const float* __restrict__ Wh1F,
        const float* __restrict__ bh1F, const float* __restrict__ Wh2F,
        const float* __restrict__ bh2F, void* __restrict__ out, const int* __restrict__ flags){
    int lane = threadIdx.x;
    float acc = 0.f;
    if (lane < 10){
        acc = bh1F[lane];
        for (int d = 0; d < 256; ++d)
            acc += __uint_as_float(pool[d]) * Wh1F[d * 10 + lane];
        acc = fmaxf(acc, 0.f) * Wh2F[lane];
    }
    #pragma unroll
    for (int o = 32; o > 0; o >>= 1) acc += __shfl_xor(acc, o);
    if (lane == 0){
        float r = acc + bh2F[0];
        if (flags[0]) ((short*)out)[0] = f2b(r);
        else          ((float*)out)[0] = r;
    }
}

extern "C" void kernel_launch(void* const* d_in, const int* in_sizes, int n_in,
                              void* d_out, int out_size, void* d_ws, size_t ws_size,
                              hipStream_t stream){
    const void* feat = d_in[0];
    const void* ei   = d_in[1];
    const void* ea   = d_in[2];
    const void* Wl[3] = {d_in[3], d_in[8],  d_in[13]};
    const void* Wr[3] = {d_in[4], d_in[9],  d_in[14]};
    const void* We[3] = {d_in[5], d_in[10], d_in[15]};
    const void* at[3] = {d_in[6], d_in[11], d_in[16]};
    const void* bb[3] = {d_in[7], d_in[12], d_in[17]};
    const void* Wh1 = d_in[18];
    const void* bh1 = d_in[19];
    const void* Wh2 = d_in[20];
    const void* bh2 = d_in[21];

    const int N = in_sizes[0] / 128;
    const int E = in_sizes[1] / 2;
    const int Kin[3] = {128, 256, 256};
    const int nb = (N + 1023) / 1024;

    char* p = (char*)d_ws;
    auto alloc = [&](size_t bytes) -> void* {
        void* r = (void*)p; p += (bytes + 255) & ~(size_t)255; return r;
    };
    int*   flags   = (int*)alloc(256);
    int*   partial = (int*)alloc(256 * 4);
    int*   off   = (int*)alloc((size_t)(N + 1) * 4);
    int*   cnt   = (int*)alloc((size_t)N * 4);
    int*   fill  = (int*)alloc((size_t)N * 4);
    int*   srcS  = (int*)alloc((size_t)E * 4);
    float* eaS   = (float*)alloc((size_t)E * 4);
    float* PR    = (float*)alloc((size_t)N * 512 * 4);
    short* QHi   = (short*)alloc((size_t)N * 256 * 2);
    short* QLo   = (short*)alloc((size_t)N * 256 * 2);
    short* BtH[3]; short* BtL[3];
    for (int i = 0; i < 3; i++){
        BtH[i] = (short*)alloc((size_t)512 * Kin[i] * 2);
        BtL[i] = (short*)alloc((size_t)512 * Kin[i] * 2);
    }
    float* WeF  = (float*)alloc(3 * 256 * 4);
    float* attF = (float*)alloc(3 * 256 * 4);
    float* bbF  = (float*)alloc(3 * 256 * 4);
    float* Wh1F = (float*)alloc(2560 * 4);
    float* bh1F = (float*)alloc(16 * 4);
    float* Wh2F = (float*)alloc(16 * 4);
    float* bh2F = (float*)alloc(4 * 4);
    unsigned* pool = (unsigned*)alloc(256 * 4);
    size_t need = (size_t)(p - (char*)d_ws);

    setup_kernel<<<dim3((N + 255) / 256), dim3(256), 0, stream>>>(feat, ei, N, flags,
                                                                  cnt, fill, pool, d_out);
    if (need > ws_size){
        sentinel_kernel<<<dim3(1), dim3(1), 0, stream>>>(d_out, flags, 555.0f);
        return;
    }

    hist_kernel<<<dim3((E + 255) / 256), dim3(256), 0, stream>>>(ei, cnt, E, flags);
    scanA<<<dim3(nb), dim3(1024), 0, stream>>>(cnt, off, partial, N);
    scanB<<<dim3(1), dim3(64), 0, stream>>>(partial, off, nb, N);
    scanC<<<dim3(nb), dim3(1024), 0, stream>>>(off, partial, N);
    scatter_kernel<<<dim3((E + 255) / 256), dim3(256), 0, stream>>>(ei, ea, off, fill,
                                                                    srcS, eaS, E, flags);
    PJobs pj;
    for (int i = 0; i < 3; i++){
        pj.W[2 * i]     = Wl[i];
        pj.bhi[2 * i]   = BtH[i];
        pj.blo[2 * i]   = BtL[i];
        pj.W[2 * i + 1]   = Wr[i];
        pj.bhi[2 * i + 1] = BtH[i] + (size_t)256 * Kin[i];
        pj.blo[2 * i + 1] = BtL[i] + (size_t)256 * Kin[i];
        pj.K[2 * i] = pj.K[2 * i + 1] = Kin[i];
        pj.fidx[2 * i] = pj.fidx[2 * i + 1] = 8 + i;
    }
    prep_all<<<dim3(256, 6), dim3(256), 0, stream>>>(pj, flags);

    DJobs jobs;
    for (int i = 0; i < 3; i++){
        jobs.j[i]     = { We[i], WeF  + i * 256, 256 };
        jobs.j[3 + i] = { at[i], attF + i * 256, 256 };
        jobs.j[6 + i] = { bb[i], bbF  + i * 256, 256 };
    }
    jobs.j[9]  = { Wh1, Wh1F, 2560 };
    jobs.j[10] = { bh1, bh1F, 10 };
    jobs.j[11] = { Wh2, Wh2F, 10 };
    jobs.j[12] = { bh2, bh2F, 1 };
    decode_many<<<dim3(13), dim3(256), 0, stream>>>(jobs, flags);

    dim3 gemm_grid((N + 127) / 128, 4);
    for (int L = 0; L < 3; L++){
        const void* A = (L == 0) ? feat : (const void*)QHi;
        int aRaw = (L == 0) ? 1 : 0;
        if (L == 0){
            gemm_tpl<1,1><<<gemm_grid, dim3(256), 0, stream>>>(A, QLo, aRaw, BtH[L], BtL[L],
                                                               PR, N, Kin[L], flags, &flags[8 + L]);
            gemm_tpl<0,1><<<gemm_grid, dim3(256), 0, stream>>>(A, QLo, aRaw, BtH[L], BtL[L],
                                                               PR, N, Kin[L], flags, &flags[8 + L]);
        } else {
            gemm_tpl<0,1><<<gemm_grid, dim3(256), 0, stream>>>(A, QLo, aRaw, BtH[L], BtL[L],
                                                               PR, N, Kin[L], flags, &flags[8 + L]);
        }
        gemm_tpl<0,0><<<gemm_grid, dim3(256), 0, stream>>>(A, QLo, aRaw, BtH[L], BtL[L],
                                                           PR, N, Kin[L], flags, &flags[8 + L]);
        fused_agg<<<dim3((N + 3) / 4), dim3(256), 0, stream>>>(PR, srcS, eaS, off,
                                                               WeF + L * 256, attF + L * 256,
                                                               bbF + L * 256, QHi, QLo, N);
    }
    col_max2<<<dim3(256), dim3(256), 0, stream>>>(QHi, QLo, pool, N);
    head_kernel<<<dim3(1), dim3(64), 0, stream>>>(pool, Wh1F, bh1F, Wh2F, bh2F, d_out, flags);
    (void)n_in; (void)out_size;
}